// Round 9
// baseline (2078.467 us; speedup 1.0000x reference)
//
#include <hip/hip_runtime.h>

#define N_ 50000
#define E_ 800000
#define T_ 3
#define NG_ (T_ * N_)   // 150000 (type,dst) groups
#define EPS_ 1e-5f

__device__ __forceinline__ float gelu_f(float x) {
    return 0.5f * x * (1.0f + erff(x * 0.70710678118654752440f));
}

// ---------------- weight prep: Wl/3, mean(Wr), mean(b), identity norm ----------------
__global__ void k_prep(const float* __restrict__ Wl, const float* __restrict__ Wr,
                       const float* __restrict__ b, float* wls, float* wra, float* ba,
                       float* idA, float* idB) {
    int i = blockIdx.x * 256 + threadIdx.x;
    const float third = 1.0f / 3.0f;
    if (i < 9 * 128 * 128) wls[i] = Wl[i] * third;
    if (i < 3 * 128 * 128) {
        int l = i >> 14, rem = i & 16383;
        const float* p = Wr + l * 3 * 16384 + rem;
        wra[i] = (p[0] + p[16384] + p[32768]) * third;
    }
    if (i < 3 * 128) {
        int l = i >> 7, c = i & 127;
        const float* p = b + l * 3 * 128 + c;
        ba[i] = (p[0] + p[128] + p[256]) * third;
    }
    if (i < 128) { idA[i] = 1.0f; idB[i] = 0.0f; }
}

// ---------------- linked-list build: head[g] -> chain of global edge ids ----------------
__global__ void k_link(const int* __restrict__ EI, int* __restrict__ head, int* __restrict__ nxt) {
    int i = blockIdx.x * 256 + threadIdx.x;
    if (i >= T_ * E_) return;
    int t = i / E_, e = i - t * E_;
    int d = EI[(t * 2 + 1) * E_ + e];
    nxt[i] = atomicExch(&head[t * N_ + d], i);
}

// ---- compact lists -> csr segments; cnt/inv; wave-scanned cursor allocation ----
__global__ __launch_bounds__(256) void k_compact(
    const int* __restrict__ EI, const int* __restrict__ head, const int* __restrict__ nxt,
    int* __restrict__ cursor, int* __restrict__ cnt, int* __restrict__ rpA,
    float* __restrict__ inv, int* __restrict__ csr) {
    int tid = threadIdx.x;
    int g = blockIdx.x * 256 + tid;
    bool ok = (g < NG_);
    int lane = tid & 63;
    int c = 0;
    int h = -1;
    if (ok) {
        h = head[g];
        int e = h;
        while (e >= 0) { c++; e = nxt[e]; }
        cnt[g] = c;
        inv[g] = 1.0f / (float)(c > 0 ? c : 1);
    }
    int x = c;
    for (int off = 1; off < 64; off <<= 1) {
        int y = __shfl_up(x, off);
        if (lane >= off) x += y;
    }
    int total = __shfl(x, 63);
    int base = 0;
    if (lane == 63 && total > 0) base = atomicAdd(cursor, total);
    base = __shfl(base, 63);
    if (ok) {
        int pos = base + x - c;
        rpA[g] = pos;
        int e = h;
        while (e >= 0) {
            int t = e / E_, idx = e - t * E_;
            csr[pos++] = EI[(t * 2) * E_ + idx];
            e = nxt[e];
        }
    }
}

// ---------------- input LN + MLP (64 -> 256 -> 128) ----------------
__global__ __launch_bounds__(256) void k_inmlp(
    const float* __restrict__ xres, const float* __restrict__ gam, const float* __restrict__ bet,
    const float* __restrict__ W1, const float* __restrict__ b1,
    const float* __restrict__ W2, const float* __restrict__ b2, float* __restrict__ x0) {
    __shared__ float xr[32][68];
    __shared__ float h1[32][260];
    int tid = threadIdx.x;
    int base = blockIdx.x * 32;
    for (int i = 0; i < 2; ++i) {
        int f4 = i * 256 + tid;
        int r = f4 >> 4, c4 = f4 & 15;
        float4 v = make_float4(0.f, 0.f, 0.f, 0.f);
        int gr = base + r;
        if (gr < N_) v = *(const float4*)&xres[gr * 64 + c4 * 4];
        *(float4*)&xr[r][c4 * 4] = v;
    }
    __syncthreads();
    {   // LayerNorm: 8 lanes per row
        int r = tid >> 3, l8 = tid & 7;
        float s = 0.f;
        for (int k = l8; k < 64; k += 8) s += xr[r][k];
        s += __shfl_xor(s, 1); s += __shfl_xor(s, 2); s += __shfl_xor(s, 4);
        float mu = s * (1.0f / 64.0f);
        float v = 0.f;
        for (int k = l8; k < 64; k += 8) { float d = xr[r][k] - mu; v += d * d; }
        v += __shfl_xor(v, 1); v += __shfl_xor(v, 2); v += __shfl_xor(v, 4);
        float rs = rsqrtf(v * (1.0f / 64.0f) + EPS_);
        for (int k = l8; k < 64; k += 8)
            xr[r][k] = (xr[r][k] - mu) * rs * gam[k] + bet[k];
    }
    __syncthreads();
    {   // GEMM1 [32x64]@[64x256] -> gelu -> h1
        int tx = tid & 63, ty = tid >> 6;
        int c0 = tx * 4, r0 = ty * 8;
        float acc[8][4];
        for (int r = 0; r < 8; ++r)
            for (int j = 0; j < 4; ++j) acc[r][j] = b1[c0 + j];
        for (int k0 = 0; k0 < 64; k0 += 4) {
            float4 a[8], w[4];
            for (int r = 0; r < 8; ++r) a[r] = *(const float4*)&xr[r0 + r][k0];
            for (int kk = 0; kk < 4; ++kk) w[kk] = *(const float4*)&W1[(k0 + kk) * 256 + c0];
            for (int kk = 0; kk < 4; ++kk)
                for (int r = 0; r < 8; ++r) {
                    float as = (&a[r].x)[kk];
                    acc[r][0] = fmaf(as, w[kk].x, acc[r][0]);
                    acc[r][1] = fmaf(as, w[kk].y, acc[r][1]);
                    acc[r][2] = fmaf(as, w[kk].z, acc[r][2]);
                    acc[r][3] = fmaf(as, w[kk].w, acc[r][3]);
                }
        }
        for (int r = 0; r < 8; ++r)
            for (int j = 0; j < 4; ++j) h1[r0 + r][c0 + j] = gelu_f(acc[r][j]);
    }
    __syncthreads();
    {   // GEMM2 [32x256]@[256x128] -> gelu -> x0
        int tx = tid & 31, ty = tid >> 5;
        int c0 = tx * 4, r0 = ty * 4;
        float acc[4][4];
        for (int r = 0; r < 4; ++r)
            for (int j = 0; j < 4; ++j) acc[r][j] = b2[c0 + j];
        for (int k0 = 0; k0 < 256; k0 += 4) {
            float4 a[4], w[4];
            for (int r = 0; r < 4; ++r) a[r] = *(const float4*)&h1[r0 + r][k0];
            for (int kk = 0; kk < 4; ++kk) w[kk] = *(const float4*)&W2[(k0 + kk) * 128 + c0];
            for (int kk = 0; kk < 4; ++kk)
                for (int r = 0; r < 4; ++r) {
                    float as = (&a[r].x)[kk];
                    acc[r][0] = fmaf(as, w[kk].x, acc[r][0]);
                    acc[r][1] = fmaf(as, w[kk].y, acc[r][1]);
                    acc[r][2] = fmaf(as, w[kk].z, acc[r][2]);
                    acc[r][3] = fmaf(as, w[kk].w, acc[r][3]);
                }
        }
        for (int r = 0; r < 4; ++r) {
            int gr = base + r0 + r;
            if (gr < N_) {
                float4 v = make_float4(gelu_f(acc[r][0]), gelu_f(acc[r][1]),
                                       gelu_f(acc[r][2]), gelu_f(acc[r][3]));
                *(float4*)&x0[(long)gr * 128 + c0] = v;
            }
        }
    }
}

// ---- CSR gather: agg[g] = norm-affine(inv * sum_{src} X[src]) ----
__global__ __launch_bounds__(256) void k_gather(
    const int* __restrict__ rpA, const int* __restrict__ cnt, const int* __restrict__ csr,
    const float* __restrict__ inv, const float* __restrict__ X, int ldx,
    const float* __restrict__ nA, const float* __restrict__ nB, float* __restrict__ agg) {
    int tid = threadIdx.x;
    int g = blockIdx.x * 4 + (tid >> 6);
    if (g >= NG_) return;
    int lane = tid & 63;
    int sub = lane >> 4;
    int f = (lane & 15) * 8;
    int start = rpA[g];
    int end = start + cnt[g];
    float4 s0 = make_float4(0.f, 0.f, 0.f, 0.f);
    float4 s1 = make_float4(0.f, 0.f, 0.f, 0.f);
    for (int e = start + sub; e < end; e += 4) {
        int sn = csr[e];
        const float* row = &X[(long)sn * ldx + f];
        const float4 v0 = *(const float4*)row;
        const float4 v1 = *(const float4*)(row + 4);
        s0.x += v0.x; s0.y += v0.y; s0.z += v0.z; s0.w += v0.w;
        s1.x += v1.x; s1.y += v1.y; s1.z += v1.z; s1.w += v1.w;
    }
    s0.x += __shfl_xor(s0.x, 16); s0.y += __shfl_xor(s0.y, 16);
    s0.z += __shfl_xor(s0.z, 16); s0.w += __shfl_xor(s0.w, 16);
    s1.x += __shfl_xor(s1.x, 16); s1.y += __shfl_xor(s1.y, 16);
    s1.z += __shfl_xor(s1.z, 16); s1.w += __shfl_xor(s1.w, 16);
    s0.x += __shfl_xor(s0.x, 32); s0.y += __shfl_xor(s0.y, 32);
    s0.z += __shfl_xor(s0.z, 32); s0.w += __shfl_xor(s0.w, 32);
    s1.x += __shfl_xor(s1.x, 32); s1.y += __shfl_xor(s1.y, 32);
    s1.z += __shfl_xor(s1.z, 32); s1.w += __shfl_xor(s1.w, 32);
    if (sub == 0) {
        float iv = inv[g];
        float bsel = (end > start) ? 1.0f : 0.0f;
        float4 A0 = *(const float4*)&nA[f];
        float4 A1 = *(const float4*)&nA[f + 4];
        float4 B0 = *(const float4*)&nB[f];
        float4 B1 = *(const float4*)&nB[f + 4];
        float* op = &agg[(long)g * 128 + f];
        *(float4*)op = make_float4(fmaf(s0.x * iv, A0.x, bsel * B0.x),
                                   fmaf(s0.y * iv, A0.y, bsel * B0.y),
                                   fmaf(s0.z * iv, A0.z, bsel * B0.z),
                                   fmaf(s0.w * iv, A0.w, bsel * B0.w));
        *(float4*)(op + 4) = make_float4(fmaf(s1.x * iv, A1.x, bsel * B1.x),
                                         fmaf(s1.y * iv, A1.y, bsel * B1.y),
                                         fmaf(s1.z * iv, A1.z, bsel * B1.z),
                                         fmaf(s1.w * iv, A1.w, bsel * B1.w));
    }
}

// ---- body GEMM: g = gelu(sum_t agg_t@(Wl_t/3) + norm(x)@Wr_avg + b_avg);
//      writes RAW g into xsave slice; accumulates colsum(g), colsum(g^2) ----
__global__ __launch_bounds__(256) void k_gemm_body(
    const float* __restrict__ X, int ldx, const float* __restrict__ agg,
    const float* __restrict__ nA, const float* __restrict__ nB,
    const float* __restrict__ wls_l, const float* __restrict__ wra_l, const float* __restrict__ ba_l,
    float* __restrict__ xsl, float* __restrict__ cs_l, float* __restrict__ cq_l) {
    __shared__ float xs[64][132];
    __shared__ float sd[8][128];
    __shared__ float sq[8][128];
    __shared__ float nAs[128], nBs[128];
    int tid = threadIdx.x;
    int base = blockIdx.x * 64;
    if (tid < 128) { nAs[tid] = nA[tid]; nBs[tid] = nB[tid]; }
    int tx = tid & 31, ty = tid >> 5;
    int c0 = tx * 4, r0 = ty * 8;
    float acc[8][4];
    for (int r = 0; r < 8; ++r)
        for (int j = 0; j < 4; ++j) acc[r][j] = ba_l[c0 + j];
    for (int seg = 0; seg < 4; ++seg) {
        const float* src; long ld;
        if (seg < 3) { src = agg + ((long)seg * N_ + base) * 128; ld = 128; }
        else         { src = X + (long)base * ldx; ld = ldx; }
        __syncthreads();
        for (int i = 0; i < 8; ++i) {
            int f4 = i * 256 + tid;
            int r = f4 >> 5, c4 = f4 & 31;
            float4 v = make_float4(0.f, 0.f, 0.f, 0.f);
            if (base + r < N_) v = *(const float4*)&src[(long)r * ld + c4 * 4];
            if (seg == 3) {
                int cc = c4 * 4;
                v.x = fmaf(v.x, nAs[cc], nBs[cc]);
                v.y = fmaf(v.y, nAs[cc + 1], nBs[cc + 1]);
                v.z = fmaf(v.z, nAs[cc + 2], nBs[cc + 2]);
                v.w = fmaf(v.w, nAs[cc + 3], nBs[cc + 3]);
            }
            *(float4*)&xs[r][c4 * 4] = v;
        }
        __syncthreads();
        const float* W = (seg < 3) ? (wls_l + seg * 16384) : wra_l;
        for (int k0 = 0; k0 < 128; k0 += 4) {
            float4 a[8], w[4];
            for (int r = 0; r < 8; ++r) a[r] = *(const float4*)&xs[r0 + r][k0];
            for (int kk = 0; kk < 4; ++kk) w[kk] = *(const float4*)&W[(k0 + kk) * 128 + c0];
            for (int kk = 0; kk < 4; ++kk)
                for (int r = 0; r < 8; ++r) {
                    float as = (&a[r].x)[kk];
                    acc[r][0] = fmaf(as, w[kk].x, acc[r][0]);
                    acc[r][1] = fmaf(as, w[kk].y, acc[r][1]);
                    acc[r][2] = fmaf(as, w[kk].z, acc[r][2]);
                    acc[r][3] = fmaf(as, w[kk].w, acc[r][3]);
                }
        }
    }
    float csum[4] = {0.f, 0.f, 0.f, 0.f};
    float qsum[4] = {0.f, 0.f, 0.f, 0.f};
    for (int r = 0; r < 8; ++r) {
        int gr = base + r0 + r;
        if (gr < N_) {
            float g0 = gelu_f(acc[r][0]), g1 = gelu_f(acc[r][1]);
            float g2 = gelu_f(acc[r][2]), g3 = gelu_f(acc[r][3]);
            *(float4*)&xsl[(long)gr * 384 + c0] = make_float4(g0, g1, g2, g3);
            csum[0] += g0; csum[1] += g1; csum[2] += g2; csum[3] += g3;
            qsum[0] += g0 * g0; qsum[1] += g1 * g1; qsum[2] += g2 * g2; qsum[3] += g3 * g3;
        }
    }
    *(float4*)&sd[ty][c0] = make_float4(csum[0], csum[1], csum[2], csum[3]);
    *(float4*)&sq[ty][c0] = make_float4(qsum[0], qsum[1], qsum[2], qsum[3]);
    __syncthreads();
    if (tid < 128) {
        float t = 0.f, q = 0.f;
        for (int i = 0; i < 8; ++i) { t += sd[i][tid]; q += sq[i][tid]; }
        atomicAdd(&cs_l[tid], t);
        atomicAdd(&cq_l[tid], q);
    }
}

// ---------------- norm coefficients: nA = rsqrt(var+eps)*gw, nB = gb - sm*nA ----------------
__global__ void k_norm(const float* __restrict__ cs_l, const float* __restrict__ cq_l,
                       const float* __restrict__ gsc, const float* __restrict__ gw,
                       const float* __restrict__ gb, float* __restrict__ nA, float* __restrict__ nB) {
    int c = threadIdx.x;
    float mu = cs_l[c] / 50000.0f;
    float sm = gsc[c] * mu;
    float var = cq_l[c] / 50000.0f - 2.0f * sm * mu + sm * sm;
    float a = rsqrtf(var + EPS_) * gw[c];
    nA[c] = a;
    nB[c] = gb[c] - sm * a;
}

// ---------------- fused head, 64-row blocks, 512 threads: norm(xsave)@Wh1..@Wo3 tanh -> xf ----
__global__ __launch_bounds__(512, 4) void k_head(const float* __restrict__ xsave,
    const float* __restrict__ nA, const float* __restrict__ nB,
    const float* __restrict__ Wh1, const float* __restrict__ bh1,
    const float* __restrict__ Wh2, const float* __restrict__ bh2,
    const float* __restrict__ xAA,
    const float* __restrict__ Wo1, const float* __restrict__ bo1,
    const float* __restrict__ Wo2, const float* __restrict__ bo2,
    const float* __restrict__ Wo3, const float* __restrict__ bo3,
    float* __restrict__ xf) {
    __shared__ __align__(16) float buf0[64 * 124];   // at-tile [64][68] then A2 [64][124]
    __shared__ __align__(16) float buf1[64 * 104];   // h1b / B2
    __shared__ float nAs[384], nBs[384];
    int tid = threadIdx.x;
    int base = blockIdx.x * 64;
    for (int i = tid; i < 384; i += 512) { nAs[i] = nA[i]; nBs[i] = nB[i]; }
    int tx = tid & 31, ty = tid >> 5;      // 16 row-groups of 4 rows
    int c0 = tx * 4, r0 = ty * 4;
    bool valid = (c0 < 100);
    float acc[4][4];
    for (int r = 0; r < 4; ++r)
        for (int j = 0; j < 4; ++j) acc[r][j] = valid ? bh1[c0 + j] : 0.f;
    for (int kt = 0; kt < 6; ++kt) {
        __syncthreads();
        for (int i = 0; i < 2; ++i) {
            int f4 = i * 512 + tid;
            int r = f4 >> 4, c4 = f4 & 15;
            int col = kt * 64 + c4 * 4;
            float4 v = make_float4(0.f, 0.f, 0.f, 0.f);
            int gr = base + r;
            if (gr < N_) v = *(const float4*)&xsave[(long)gr * 384 + col];
            v.x = fmaf(v.x, nAs[col], nBs[col]);
            v.y = fmaf(v.y, nAs[col + 1], nBs[col + 1]);
            v.z = fmaf(v.z, nAs[col + 2], nBs[col + 2]);
            v.w = fmaf(v.w, nAs[col + 3], nBs[col + 3]);
            *(float4*)&buf0[r * 68 + c4 * 4] = v;
        }
        __syncthreads();
        if (valid) {
            for (int k0 = 0; k0 < 64; k0 += 4) {
                float4 a[4], w[4];
                for (int r = 0; r < 4; ++r) a[r] = *(const float4*)&buf0[(r0 + r) * 68 + k0];
                for (int kk = 0; kk < 4; ++kk) w[kk] = *(const float4*)&Wh1[(kt * 64 + k0 + kk) * 100 + c0];
                for (int kk = 0; kk < 4; ++kk)
                    for (int r = 0; r < 4; ++r) {
                        float as = (&a[r].x)[kk];
                        acc[r][0] = fmaf(as, w[kk].x, acc[r][0]);
                        acc[r][1] = fmaf(as, w[kk].y, acc[r][1]);
                        acc[r][2] = fmaf(as, w[kk].z, acc[r][2]);
                        acc[r][3] = fmaf(as, w[kk].w, acc[r][3]);
                    }
            }
        }
    }
    __syncthreads();
    if (valid)
        for (int r = 0; r < 4; ++r)
            for (int j = 0; j < 4; ++j) buf1[(r0 + r) * 104 + c0 + j] = gelu_f(acc[r][j]);
    __syncthreads();
    // stage xAA into A2 cols 100..119 (buf0 now A2 layout, stride 124)
    {
        int f4 = tid;
        if (f4 < 320) {
            int r = f4 / 5, c4 = f4 - r * 5;
            float4 v = make_float4(0.f, 0.f, 0.f, 0.f);
            int gr = base + r;
            if (gr < N_) v = *(const float4*)&xAA[(long)gr * 20 + c4 * 4];
            *(float4*)&buf0[r * 124 + 100 + c4 * 4] = v;
        }
    }
    {   // Wh2: K=100 from buf1 -> gelu -> A2 cols 0..99
        float acc2[4][4];
        for (int r = 0; r < 4; ++r)
            for (int j = 0; j < 4; ++j) acc2[r][j] = valid ? bh2[c0 + j] : 0.f;
        if (valid) {
            for (int k0 = 0; k0 < 100; k0 += 4) {
                float4 a[4], w[4];
                for (int r = 0; r < 4; ++r) a[r] = *(const float4*)&buf1[(r0 + r) * 104 + k0];
                for (int kk = 0; kk < 4; ++kk) w[kk] = *(const float4*)&Wh2[(k0 + kk) * 100 + c0];
                for (int kk = 0; kk < 4; ++kk)
                    for (int r = 0; r < 4; ++r) {
                        float as = (&a[r].x)[kk];
                        acc2[r][0] = fmaf(as, w[kk].x, acc2[r][0]);
                        acc2[r][1] = fmaf(as, w[kk].y, acc2[r][1]);
                        acc2[r][2] = fmaf(as, w[kk].z, acc2[r][2]);
                        acc2[r][3] = fmaf(as, w[kk].w, acc2[r][3]);
                    }
            }
            for (int r = 0; r < 4; ++r)
                for (int j = 0; j < 4; ++j) buf0[(r0 + r) * 124 + c0 + j] = gelu_f(acc2[r][j]);
        }
    }
    __syncthreads();
    {   // Wo1: K=120 from A2 -> gelu -> buf1
        float acc3[4][4];
        for (int r = 0; r < 4; ++r)
            for (int j = 0; j < 4; ++j) acc3[r][j] = valid ? bo1[c0 + j] : 0.f;
        if (valid) {
            for (int k0 = 0; k0 < 120; k0 += 4) {
                float4 a[4], w[4];
                for (int r = 0; r < 4; ++r) a[r] = *(const float4*)&buf0[(r0 + r) * 124 + k0];
                for (int kk = 0; kk < 4; ++kk) w[kk] = *(const float4*)&Wo1[(k0 + kk) * 100 + c0];
                for (int kk = 0; kk < 4; ++kk)
                    for (int r = 0; r < 4; ++r) {
                        float as = (&a[r].x)[kk];
                        acc3[r][0] = fmaf(as, w[kk].x, acc3[r][0]);
                        acc3[r][1] = fmaf(as, w[kk].y, acc3[r][1]);
                        acc3[r][2] = fmaf(as, w[kk].z, acc3[r][2]);
                        acc3[r][3] = fmaf(as, w[kk].w, acc3[r][3]);
                    }
            }
        }
        __syncthreads();
        if (valid)
            for (int r = 0; r < 4; ++r)
                for (int j = 0; j < 4; ++j) buf1[(r0 + r) * 104 + c0 + j] = gelu_f(acc3[r][j]);
    }
    __syncthreads();
    {   // Wo2: K=100 from buf1 -> gelu -> A2 cols 0..99
        float acc4[4][4];
        for (int r = 0; r < 4; ++r)
            for (int j = 0; j < 4; ++j) acc4[r][j] = valid ? bo2[c0 + j] : 0.f;
        if (valid) {
            for (int k0 = 0; k0 < 100; k0 += 4) {
                float4 a[4], w[4];
                for (int r = 0; r < 4; ++r) a[r] = *(const float4*)&buf1[(r0 + r) * 104 + k0];
                for (int kk = 0; kk < 4; ++kk) w[kk] = *(const float4*)&Wo2[(k0 + kk) * 100 + c0];
                for (int kk = 0; kk < 4; ++kk)
                    for (int r = 0; r < 4; ++r) {
                        float as = (&a[r].x)[kk];
                        acc4[r][0] = fmaf(as, w[kk].x, acc4[r][0]);
                        acc4[r][1] = fmaf(as, w[kk].y, acc4[r][1]);
                        acc4[r][2] = fmaf(as, w[kk].z, acc4[r][2]);
                        acc4[r][3] = fmaf(as, w[kk].w, acc4[r][3]);
                    }
            }
        }
        __syncthreads();
        if (valid)
            for (int r = 0; r < 4; ++r)
                for (int j = 0; j < 4; ++j) buf0[(r0 + r) * 124 + c0 + j] = gelu_f(acc4[r][j]);
    }
    __syncthreads();
    {   // Wo3: K=100 from A2 -> tanh -> xf [N,32]; 1 row per 8-thread group (512 thr = 64 rows)
        int c0b = (tid & 7) * 4, row = tid >> 3;
        float acc5[4];
        for (int j = 0; j < 4; ++j) acc5[j] = bo3[c0b + j];
        for (int k0 = 0; k0 < 100; k0 += 4) {
            float4 a = *(const float4*)&buf0[row * 124 + k0];
            float4 w[4];
            for (int kk = 0; kk < 4; ++kk) w[kk] = *(const float4*)&Wo3[(k0 + kk) * 32 + c0b];
            for (int kk = 0; kk < 4; ++kk) {
                float as = (&a.x)[kk];
                acc5[0] = fmaf(as, w[kk].x, acc5[0]);
                acc5[1] = fmaf(as, w[kk].y, acc5[1]);
                acc5[2] = fmaf(as, w[kk].z, acc5[2]);
                acc5[3] = fmaf(as, w[kk].w, acc5[3]);
            }
        }
        int gr = base + row;
        if (gr < N_) {
            float4 v = make_float4(tanhf(acc5[0]), tanhf(acc5[1]), tanhf(acc5[2]), tanhf(acc5[3]));
            *(float4*)&xf[(long)gr * 32 + c0b] = v;
        }
    }
}

// ---------------- VQ: 1 thread per node, codebook in LDS ----------------
__global__ __launch_bounds__(256) void k_vq(const float* __restrict__ xf,
    const float* __restrict__ cb, float* __restrict__ zq, float* __restrict__ loss) {
    __shared__ float CB[128 * 32];
    __shared__ float CC[128];
    __shared__ float SR[256];
    int tid = threadIdx.x;
    for (int i = 0; i < 4; ++i) {
        int f4 = i * 256 + tid;
        *(float4*)&CB[f4 * 4] = *(const float4*)&cb[f4 * 4];
    }
    __syncthreads();
    if (tid < 128) {
        float s = 0.f;
        for (int j = 0; j < 32; ++j) { float v = CB[tid * 32 + j]; s += v * v; }
        CC[tid] = s;
    }
    __syncthreads();
    int node = blockIdx.x * 256 + tid;
    float part = 0.f;
    if (node < N_) {
        float4 xv[8];
        for (int j4 = 0; j4 < 8; ++j4) xv[j4] = *(const float4*)&xf[(long)node * 32 + j4 * 4];
        float xx = 0.f;
        for (int j4 = 0; j4 < 8; ++j4)
            xx += xv[j4].x * xv[j4].x + xv[j4].y * xv[j4].y + xv[j4].z * xv[j4].z + xv[j4].w * xv[j4].w;
        float best = 3.4e38f;
        int bidx = 0;
        for (int k = 0; k < 128; ++k) {
            const float* cbr = &CB[k * 32];
            float dot = 0.f;
            for (int j4 = 0; j4 < 8; ++j4) {
                float4 cv = *(const float4*)&cbr[j4 * 4];
                dot += cv.x * xv[j4].x + cv.y * xv[j4].y + cv.z * xv[j4].z + cv.w * xv[j4].w;
            }
            float d = fmaf(-2.0f, dot, xx) + CC[k];
            if (d < best) { best = d; bidx = k; }
        }
        const float* q = &CB[bidx * 32];
        for (int j4 = 0; j4 < 8; ++j4) {
            float4 qv = *(const float4*)&q[j4 * 4];
            *(float4*)&zq[(long)node * 32 + j4 * 4] = qv;
            float4 xvv = xv[j4];
            float d0 = qv.x - xvv.x, d1 = qv.y - xvv.y, d2 = qv.z - xvv.z, d3 = qv.w - xvv.w;
            part += d0 * d0 + d1 * d1 + d2 * d2 + d3 * d3;
        }
    }
    SR[tid] = part;
    __syncthreads();
    for (int off = 128; off > 0; off >>= 1) {
        if (tid < off) SR[tid] += SR[tid + off];
        __syncthreads();
    }
    if (tid == 0) atomicAdd(loss, SR[0]);
}

__global__ void k_fin(float* dout, const float* loss) {
    if (threadIdx.x == 0 && blockIdx.x == 0)
        dout[(long)N_ * 32] = 1.25f * (loss[0] / 1600000.0f);
}

extern "C" void kernel_launch(void* const* d_in, const int* in_sizes, int n_in,
                              void* d_out, int out_size, void* d_ws, size_t ws_size,
                              hipStream_t stream) {
    const float* x_res = (const float*)d_in[0];
    const float* x_AA  = (const float*)d_in[1];
    const int*   EI    = (const int*)d_in[2];
    const float* ln_g  = (const float*)d_in[3];
    const float* ln_b  = (const float*)d_in[4];
    const float* W1    = (const float*)d_in[5];
    const float* b1    = (const float*)d_in[6];
    const float* W2    = (const float*)d_in[7];
    const float* b2    = (const float*)d_in[8];
    const float* sWl   = (const float*)d_in[9];
    const float* sWr   = (const float*)d_in[10];
    const float* sb    = (const float*)d_in[11];
    const float* gnw   = (const float*)d_in[12];
    const float* gnb   = (const float*)d_in[13];
    const float* gns   = (const float*)d_in[14];
    const float* Wh1   = (const float*)d_in[15];
    const float* bh1   = (const float*)d_in[16];
    const float* Wh2   = (const float*)d_in[17];
    const float* bh2   = (const float*)d_in[18];
    const float* Wo1   = (const float*)d_in[19];
    const float* bo1   = (const float*)d_in[20];
    const float* Wo2   = (const float*)d_in[21];
    const float* bo2   = (const float*)d_in[22];
    const float* Wo3   = (const float*)d_in[23];
    const float* bo3   = (const float*)d_in[24];
    const float* cbk   = (const float*)d_in[25];
    float* out = (float*)d_out;

    float* ws    = (float*)d_ws;
    float* xsave = ws;                               // N*384 (raw g per layer slice)
    float* x0    = xsave + (size_t)N_ * 384;         // N*128 (later reused as xf)
    float* agg   = x0 + (size_t)N_ * 128;            // 3*N*128
    float* wls   = agg + (size_t)3 * N_ * 128;       // 147456
    float* wra   = wls + 147456;                     // 49152
    float* ba    = wra + 49152;                      // 384
    float* idA   = ba + 384;                         // 128
    float* idB   = idA + 128;                        // 128
    float* normA = idB + 128;                        // 3*128
    float* normB = normA + 384;                      // 3*128
    // zero-init region: [cursor 1][loss 1][cs 3*128][cq 3*128]
    int*   cursor = (int*)(normB + 384);             // 1
    float* loss  = (float*)(cursor + 1);             // 1
    float* cs    = loss + 1;                         // 3*128
    float* cq    = cs + 384;                         // 3*128
    int*   head  = (int*)(cq + 384);                 // NG_  (memset 0xFF)
    int*   nxt   = head + NG_;                       // T_*E_
    int*   cnt   = nxt + (size_t)T_ * E_;            // NG_
    int*   rpA   = cnt + NG_;                        // NG_
    float* inv   = (float*)(rpA + NG_);              // NG_
    int*   csr   = (int*)(inv + NG_);                // T_*E_
    float* xf    = x0;                               // reuse x0 (dead after layer 0)

    hipMemsetAsync(cursor, 0, 770 * sizeof(int), stream);
    hipMemsetAsync(head, 0xFF, NG_ * sizeof(int), stream);

    k_prep<<<576, 256, 0, stream>>>(sWl, sWr, sb, wls, wra, ba, idA, idB);
    k_link<<<(T_ * E_ + 255) / 256, 256, 0, stream>>>(EI, head, nxt);
    k_compact<<<(NG_ + 255) / 256, 256, 0, stream>>>(EI, head, nxt, cursor, cnt, rpA, inv, csr);
    k_inmlp<<<(N_ + 31) / 32, 256, 0, stream>>>(x_res, ln_g, ln_b, W1, b1, W2, b2, x0);

    for (int l = 0; l < 3; ++l) {
        const float* X = (l == 0) ? x0 : (xsave + (size_t)(l - 1) * 128);
        int ldx = (l == 0) ? 128 : 384;
        const float* nAl = (l == 0) ? idA : (normA + (size_t)(l - 1) * 128);
        const float* nBl = (l == 0) ? idB : (normB + (size_t)(l - 1) * 128);
        k_gather<<<NG_ / 4, 256, 0, stream>>>(rpA, cnt, csr, inv, X, ldx, nAl, nBl, agg);
        k_gemm_body<<<(N_ + 63) / 64, 256, 0, stream>>>(X, ldx, agg, nAl, nBl,
            wls + (size_t)l * 3 * 16384, wra + (size_t)l * 16384, ba + l * 128,
            xsave + (size_t)l * 128, cs + l * 128, cq + l * 128);
        k_norm<<<1, 128, 0, stream>>>(cs + l * 128, cq + l * 128, gns + l * 128,
                                      gnw + l * 128, gnb + l * 128,
                                      normA + (size_t)l * 128, normB + (size_t)l * 128);
    }
    k_head<<<(N_ + 63) / 64, 512, 0, stream>>>(xsave, normA, normB, Wh1, bh1, Wh2, bh2,
                                               x_AA, Wo1, bo1, Wo2, bo2, Wo3, bo3, xf);
    k_vq<<<(N_ + 255) / 256, 256, 0, stream>>>(xf, cbk, out, loss);
    k_fin<<<1, 64, 0, stream>>>(out, loss);
}

// Round 10
// 2073.401 us; speedup vs baseline: 1.0024x; 1.0024x over previous
//
#include <hip/hip_runtime.h>

#define N_ 50000
#define E_ 800000
#define T_ 3
#define NG_ (T_ * N_)   // 150000 (type,dst) groups
#define EPS_ 1e-5f

__device__ __forceinline__ float gelu_f(float x) {
    return 0.5f * x * (1.0f + erff(x * 0.70710678118654752440f));
}

// ---------------- weight prep: Wl/3, mean(Wr), mean(b), identity norm ----------------
__global__ void k_prep(const float* __restrict__ Wl, const float* __restrict__ Wr,
                       const float* __restrict__ b, float* wls, float* wra, float* ba,
                       float* idA, float* idB) {
    int i = blockIdx.x * 256 + threadIdx.x;
    const float third = 1.0f / 3.0f;
    if (i < 9 * 128 * 128) wls[i] = Wl[i] * third;
    if (i < 3 * 128 * 128) {
        int l = i >> 14, rem = i & 16383;
        const float* p = Wr + l * 3 * 16384 + rem;
        wra[i] = (p[0] + p[16384] + p[32768]) * third;
    }
    if (i < 3 * 128) {
        int l = i >> 7, c = i & 127;
        const float* p = b + l * 3 * 128 + c;
        ba[i] = (p[0] + p[128] + p[256]) * third;
    }
    if (i < 128) { idA[i] = 1.0f; idB[i] = 0.0f; }
}

// ---------------- linked-list build: head[g] -> chain of global edge ids ----------------
__global__ void k_link(const int* __restrict__ EI, int* __restrict__ head, int* __restrict__ nxt) {
    int i = blockIdx.x * 256 + threadIdx.x;
    if (i >= T_ * E_) return;
    int t = i / E_, e = i - t * E_;
    int d = EI[(t * 2 + 1) * E_ + e];
    nxt[i] = atomicExch(&head[t * N_ + d], i);
}

// ---- compact lists -> csr segments; cnt/inv; wave-scanned cursor allocation ----
__global__ __launch_bounds__(256) void k_compact(
    const int* __restrict__ EI, const int* __restrict__ head, const int* __restrict__ nxt,
    int* __restrict__ cursor, int* __restrict__ cnt, int* __restrict__ rpA,
    float* __restrict__ inv, int* __restrict__ csr) {
    int tid = threadIdx.x;
    int g = blockIdx.x * 256 + tid;
    bool ok = (g < NG_);
    int lane = tid & 63;
    int c = 0;
    int h = -1;
    if (ok) {
        h = head[g];
        int e = h;
        while (e >= 0) { c++; e = nxt[e]; }
        cnt[g] = c;
        inv[g] = 1.0f / (float)(c > 0 ? c : 1);
    }
    int x = c;
    for (int off = 1; off < 64; off <<= 1) {
        int y = __shfl_up(x, off);
        if (lane >= off) x += y;
    }
    int total = __shfl(x, 63);
    int base = 0;
    if (lane == 63 && total > 0) base = atomicAdd(cursor, total);
    base = __shfl(base, 63);
    if (ok) {
        int pos = base + x - c;
        rpA[g] = pos;
        int e = h;
        while (e >= 0) {
            int t = e / E_, idx = e - t * E_;
            csr[pos++] = EI[(t * 2) * E_ + idx];
            e = nxt[e];
        }
    }
}

// ---------------- input LN + MLP (64 -> 256 -> 128) ----------------
__global__ __launch_bounds__(256) void k_inmlp(
    const float* __restrict__ xres, const float* __restrict__ gam, const float* __restrict__ bet,
    const float* __restrict__ W1, const float* __restrict__ b1,
    const float* __restrict__ W2, const float* __restrict__ b2, float* __restrict__ x0) {
    __shared__ float xr[32][68];
    __shared__ float h1[32][260];
    int tid = threadIdx.x;
    int base = blockIdx.x * 32;
    for (int i = 0; i < 2; ++i) {
        int f4 = i * 256 + tid;
        int r = f4 >> 4, c4 = f4 & 15;
        float4 v = make_float4(0.f, 0.f, 0.f, 0.f);
        int gr = base + r;
        if (gr < N_) v = *(const float4*)&xres[gr * 64 + c4 * 4];
        *(float4*)&xr[r][c4 * 4] = v;
    }
    __syncthreads();
    {   // LayerNorm: 8 lanes per row
        int r = tid >> 3, l8 = tid & 7;
        float s = 0.f;
        for (int k = l8; k < 64; k += 8) s += xr[r][k];
        s += __shfl_xor(s, 1); s += __shfl_xor(s, 2); s += __shfl_xor(s, 4);
        float mu = s * (1.0f / 64.0f);
        float v = 0.f;
        for (int k = l8; k < 64; k += 8) { float d = xr[r][k] - mu; v += d * d; }
        v += __shfl_xor(v, 1); v += __shfl_xor(v, 2); v += __shfl_xor(v, 4);
        float rs = rsqrtf(v * (1.0f / 64.0f) + EPS_);
        for (int k = l8; k < 64; k += 8)
            xr[r][k] = (xr[r][k] - mu) * rs * gam[k] + bet[k];
    }
    __syncthreads();
    {   // GEMM1 [32x64]@[64x256] -> gelu -> h1
        int tx = tid & 63, ty = tid >> 6;
        int c0 = tx * 4, r0 = ty * 8;
        float acc[8][4];
        for (int r = 0; r < 8; ++r)
            for (int j = 0; j < 4; ++j) acc[r][j] = b1[c0 + j];
        for (int k0 = 0; k0 < 64; k0 += 4) {
            float4 a[8], w[4];
            for (int r = 0; r < 8; ++r) a[r] = *(const float4*)&xr[r0 + r][k0];
            for (int kk = 0; kk < 4; ++kk) w[kk] = *(const float4*)&W1[(k0 + kk) * 256 + c0];
            for (int kk = 0; kk < 4; ++kk)
                for (int r = 0; r < 8; ++r) {
                    float as = (&a[r].x)[kk];
                    acc[r][0] = fmaf(as, w[kk].x, acc[r][0]);
                    acc[r][1] = fmaf(as, w[kk].y, acc[r][1]);
                    acc[r][2] = fmaf(as, w[kk].z, acc[r][2]);
                    acc[r][3] = fmaf(as, w[kk].w, acc[r][3]);
                }
        }
        for (int r = 0; r < 8; ++r)
            for (int j = 0; j < 4; ++j) h1[r0 + r][c0 + j] = gelu_f(acc[r][j]);
    }
    __syncthreads();
    {   // GEMM2 [32x256]@[256x128] -> gelu -> x0
        int tx = tid & 31, ty = tid >> 5;
        int c0 = tx * 4, r0 = ty * 4;
        float acc[4][4];
        for (int r = 0; r < 4; ++r)
            for (int j = 0; j < 4; ++j) acc[r][j] = b2[c0 + j];
        for (int k0 = 0; k0 < 256; k0 += 4) {
            float4 a[4], w[4];
            for (int r = 0; r < 4; ++r) a[r] = *(const float4*)&h1[r0 + r][k0];
            for (int kk = 0; kk < 4; ++kk) w[kk] = *(const float4*)&W2[(k0 + kk) * 128 + c0];
            for (int kk = 0; kk < 4; ++kk)
                for (int r = 0; r < 4; ++r) {
                    float as = (&a[r].x)[kk];
                    acc[r][0] = fmaf(as, w[kk].x, acc[r][0]);
                    acc[r][1] = fmaf(as, w[kk].y, acc[r][1]);
                    acc[r][2] = fmaf(as, w[kk].z, acc[r][2]);
                    acc[r][3] = fmaf(as, w[kk].w, acc[r][3]);
                }
        }
        for (int r = 0; r < 4; ++r) {
            int gr = base + r0 + r;
            if (gr < N_) {
                float4 v = make_float4(gelu_f(acc[r][0]), gelu_f(acc[r][1]),
                                       gelu_f(acc[r][2]), gelu_f(acc[r][3]));
                *(float4*)&x0[(long)gr * 128 + c0] = v;
            }
        }
    }
}

// ---- CSR gather: agg[g] = norm-affine(inv * sum_{src} X[src]) ----
__global__ __launch_bounds__(256) void k_gather(
    const int* __restrict__ rpA, const int* __restrict__ cnt, const int* __restrict__ csr,
    const float* __restrict__ inv, const float* __restrict__ X, int ldx,
    const float* __restrict__ nA, const float* __restrict__ nB, float* __restrict__ agg) {
    int tid = threadIdx.x;
    int g = blockIdx.x * 4 + (tid >> 6);
    if (g >= NG_) return;
    int lane = tid & 63;
    int sub = lane >> 4;
    int f = (lane & 15) * 8;
    int start = rpA[g];
    int end = start + cnt[g];
    float4 s0 = make_float4(0.f, 0.f, 0.f, 0.f);
    float4 s1 = make_float4(0.f, 0.f, 0.f, 0.f);
    for (int e = start + sub; e < end; e += 4) {
        int sn = csr[e];
        const float* row = &X[(long)sn * ldx + f];
        const float4 v0 = *(const float4*)row;
        const float4 v1 = *(const float4*)(row + 4);
        s0.x += v0.x; s0.y += v0.y; s0.z += v0.z; s0.w += v0.w;
        s1.x += v1.x; s1.y += v1.y; s1.z += v1.z; s1.w += v1.w;
    }
    s0.x += __shfl_xor(s0.x, 16); s0.y += __shfl_xor(s0.y, 16);
    s0.z += __shfl_xor(s0.z, 16); s0.w += __shfl_xor(s0.w, 16);
    s1.x += __shfl_xor(s1.x, 16); s1.y += __shfl_xor(s1.y, 16);
    s1.z += __shfl_xor(s1.z, 16); s1.w += __shfl_xor(s1.w, 16);
    s0.x += __shfl_xor(s0.x, 32); s0.y += __shfl_xor(s0.y, 32);
    s0.z += __shfl_xor(s0.z, 32); s0.w += __shfl_xor(s0.w, 32);
    s1.x += __shfl_xor(s1.x, 32); s1.y += __shfl_xor(s1.y, 32);
    s1.z += __shfl_xor(s1.z, 32); s1.w += __shfl_xor(s1.w, 32);
    if (sub == 0) {
        float iv = inv[g];
        float bsel = (end > start) ? 1.0f : 0.0f;
        float4 A0 = *(const float4*)&nA[f];
        float4 A1 = *(const float4*)&nA[f + 4];
        float4 B0 = *(const float4*)&nB[f];
        float4 B1 = *(const float4*)&nB[f + 4];
        float* op = &agg[(long)g * 128 + f];
        *(float4*)op = make_float4(fmaf(s0.x * iv, A0.x, bsel * B0.x),
                                   fmaf(s0.y * iv, A0.y, bsel * B0.y),
                                   fmaf(s0.z * iv, A0.z, bsel * B0.z),
                                   fmaf(s0.w * iv, A0.w, bsel * B0.w));
        *(float4*)(op + 4) = make_float4(fmaf(s1.x * iv, A1.x, bsel * B1.x),
                                         fmaf(s1.y * iv, A1.y, bsel * B1.y),
                                         fmaf(s1.z * iv, A1.z, bsel * B1.z),
                                         fmaf(s1.w * iv, A1.w, bsel * B1.w));
    }
}

// ---- body GEMM: g = gelu(sum_t agg_t@(Wl_t/3) + norm(x)@Wr_avg + b_avg);
//      writes RAW g into xsave slice; accumulates colsum(g), colsum(g^2) ----
__global__ __launch_bounds__(256) void k_gemm_body(
    const float* __restrict__ X, int ldx, const float* __restrict__ agg,
    const float* __restrict__ nA, const float* __restrict__ nB,
    const float* __restrict__ wls_l, const float* __restrict__ wra_l, const float* __restrict__ ba_l,
    float* __restrict__ xsl, float* __restrict__ cs_l, float* __restrict__ cq_l) {
    __shared__ float xs[64][132];
    __shared__ float sd[8][128];
    __shared__ float sq[8][128];
    __shared__ float nAs[128], nBs[128];
    int tid = threadIdx.x;
    int base = blockIdx.x * 64;
    if (tid < 128) { nAs[tid] = nA[tid]; nBs[tid] = nB[tid]; }
    int tx = tid & 31, ty = tid >> 5;
    int c0 = tx * 4, r0 = ty * 8;
    float acc[8][4];
    for (int r = 0; r < 8; ++r)
        for (int j = 0; j < 4; ++j) acc[r][j] = ba_l[c0 + j];
    for (int seg = 0; seg < 4; ++seg) {
        const float* src; long ld;
        if (seg < 3) { src = agg + ((long)seg * N_ + base) * 128; ld = 128; }
        else         { src = X + (long)base * ldx; ld = ldx; }
        __syncthreads();
        for (int i = 0; i < 8; ++i) {
            int f4 = i * 256 + tid;
            int r = f4 >> 5, c4 = f4 & 31;
            float4 v = make_float4(0.f, 0.f, 0.f, 0.f);
            if (base + r < N_) v = *(const float4*)&src[(long)r * ld + c4 * 4];
            if (seg == 3) {
                int cc = c4 * 4;
                v.x = fmaf(v.x, nAs[cc], nBs[cc]);
                v.y = fmaf(v.y, nAs[cc + 1], nBs[cc + 1]);
                v.z = fmaf(v.z, nAs[cc + 2], nBs[cc + 2]);
                v.w = fmaf(v.w, nAs[cc + 3], nBs[cc + 3]);
            }
            *(float4*)&xs[r][c4 * 4] = v;
        }
        __syncthreads();
        const float* W = (seg < 3) ? (wls_l + seg * 16384) : wra_l;
        for (int k0 = 0; k0 < 128; k0 += 4) {
            float4 a[8], w[4];
            for (int r = 0; r < 8; ++r) a[r] = *(const float4*)&xs[r0 + r][k0];
            for (int kk = 0; kk < 4; ++kk) w[kk] = *(const float4*)&W[(k0 + kk) * 128 + c0];
            for (int kk = 0; kk < 4; ++kk)
                for (int r = 0; r < 8; ++r) {
                    float as = (&a[r].x)[kk];
                    acc[r][0] = fmaf(as, w[kk].x, acc[r][0]);
                    acc[r][1] = fmaf(as, w[kk].y, acc[r][1]);
                    acc[r][2] = fmaf(as, w[kk].z, acc[r][2]);
                    acc[r][3] = fmaf(as, w[kk].w, acc[r][3]);
                }
        }
    }
    float csum[4] = {0.f, 0.f, 0.f, 0.f};
    float qsum[4] = {0.f, 0.f, 0.f, 0.f};
    for (int r = 0; r < 8; ++r) {
        int gr = base + r0 + r;
        if (gr < N_) {
            float g0 = gelu_f(acc[r][0]), g1 = gelu_f(acc[r][1]);
            float g2 = gelu_f(acc[r][2]), g3 = gelu_f(acc[r][3]);
            *(float4*)&xsl[(long)gr * 384 + c0] = make_float4(g0, g1, g2, g3);
            csum[0] += g0; csum[1] += g1; csum[2] += g2; csum[3] += g3;
            qsum[0] += g0 * g0; qsum[1] += g1 * g1; qsum[2] += g2 * g2; qsum[3] += g3 * g3;
        }
    }
    *(float4*)&sd[ty][c0] = make_float4(csum[0], csum[1], csum[2], csum[3]);
    *(float4*)&sq[ty][c0] = make_float4(qsum[0], qsum[1], qsum[2], qsum[3]);
    __syncthreads();
    if (tid < 128) {
        float t = 0.f, q = 0.f;
        for (int i = 0; i < 8; ++i) { t += sd[i][tid]; q += sq[i][tid]; }
        atomicAdd(&cs_l[tid], t);
        atomicAdd(&cq_l[tid], q);
    }
}

// ---------------- norm coefficients: nA = rsqrt(var+eps)*gw, nB = gb - sm*nA ----------------
__global__ void k_norm(const float* __restrict__ cs_l, const float* __restrict__ cq_l,
                       const float* __restrict__ gsc, const float* __restrict__ gw,
                       const float* __restrict__ gb, float* __restrict__ nA, float* __restrict__ nB) {
    int c = threadIdx.x;
    float mu = cs_l[c] / 50000.0f;
    float sm = gsc[c] * mu;
    float var = cq_l[c] / 50000.0f - 2.0f * sm * mu + sm * sm;
    float a = rsqrtf(var + EPS_) * gw[c];
    nA[c] = a;
    nB[c] = gb[c] - sm * a;
}

// ---------------- fused head, 32-row blocks, 256 threads, VGPR cap 128 ----------------
__global__ __launch_bounds__(256, 4) void k_head(const float* __restrict__ xsave,
    const float* __restrict__ nA, const float* __restrict__ nB,
    const float* __restrict__ Wh1, const float* __restrict__ bh1,
    const float* __restrict__ Wh2, const float* __restrict__ bh2,
    const float* __restrict__ xAA,
    const float* __restrict__ Wo1, const float* __restrict__ bo1,
    const float* __restrict__ Wo2, const float* __restrict__ bo2,
    const float* __restrict__ Wo3, const float* __restrict__ bo3,
    float* __restrict__ xf) {
    __shared__ __align__(16) float buf0[32 * 124];   // at-tile [32][68] then A2 [32][124]
    __shared__ __align__(16) float buf1[32 * 104];   // h1b / B2
    __shared__ float nAs[384], nBs[384];
    int tid = threadIdx.x;
    int base = blockIdx.x * 32;
    for (int i = tid; i < 384; i += 256) { nAs[i] = nA[i]; nBs[i] = nB[i]; }
    int tx = tid & 31, ty = tid >> 5;
    int c0 = tx * 4, r0 = ty * 4;
    bool valid = (c0 < 100);
    float acc[4][4];
    for (int r = 0; r < 4; ++r)
        for (int j = 0; j < 4; ++j) acc[r][j] = valid ? bh1[c0 + j] : 0.f;
    for (int kt = 0; kt < 6; ++kt) {
        __syncthreads();
        for (int i = 0; i < 2; ++i) {
            int f4 = i * 256 + tid;
            int r = f4 >> 4, c4 = f4 & 15;
            int col = kt * 64 + c4 * 4;
            float4 v = make_float4(0.f, 0.f, 0.f, 0.f);
            int gr = base + r;
            if (gr < N_) v = *(const float4*)&xsave[(long)gr * 384 + col];
            v.x = fmaf(v.x, nAs[col], nBs[col]);
            v.y = fmaf(v.y, nAs[col + 1], nBs[col + 1]);
            v.z = fmaf(v.z, nAs[col + 2], nBs[col + 2]);
            v.w = fmaf(v.w, nAs[col + 3], nBs[col + 3]);
            *(float4*)&buf0[r * 68 + c4 * 4] = v;
        }
        __syncthreads();
        if (valid) {
            for (int k0 = 0; k0 < 64; k0 += 4) {
                float4 a[4], w[4];
                for (int r = 0; r < 4; ++r) a[r] = *(const float4*)&buf0[(r0 + r) * 68 + k0];
                for (int kk = 0; kk < 4; ++kk) w[kk] = *(const float4*)&Wh1[(kt * 64 + k0 + kk) * 100 + c0];
                for (int kk = 0; kk < 4; ++kk)
                    for (int r = 0; r < 4; ++r) {
                        float as = (&a[r].x)[kk];
                        acc[r][0] = fmaf(as, w[kk].x, acc[r][0]);
                        acc[r][1] = fmaf(as, w[kk].y, acc[r][1]);
                        acc[r][2] = fmaf(as, w[kk].z, acc[r][2]);
                        acc[r][3] = fmaf(as, w[kk].w, acc[r][3]);
                    }
            }
        }
    }
    __syncthreads();
    if (valid)
        for (int r = 0; r < 4; ++r)
            for (int j = 0; j < 4; ++j) buf1[(r0 + r) * 104 + c0 + j] = gelu_f(acc[r][j]);
    __syncthreads();
    // stage xAA into A2 cols 100..119 (buf0 now A2 layout, stride 124)
    {
        int f4 = tid;
        if (f4 < 160) {
            int r = f4 / 5, c4 = f4 - r * 5;
            float4 v = make_float4(0.f, 0.f, 0.f, 0.f);
            int gr = base + r;
            if (gr < N_) v = *(const float4*)&xAA[(long)gr * 20 + c4 * 4];
            *(float4*)&buf0[r * 124 + 100 + c4 * 4] = v;
        }
    }
    {   // Wh2: K=100 from buf1 -> gelu -> A2 cols 0..99
        float acc2[4][4];
        for (int r = 0; r < 4; ++r)
            for (int j = 0; j < 4; ++j) acc2[r][j] = valid ? bh2[c0 + j] : 0.f;
        if (valid) {
            for (int k0 = 0; k0 < 100; k0 += 4) {
                float4 a[4], w[4];
                for (int r = 0; r < 4; ++r) a[r] = *(const float4*)&buf1[(r0 + r) * 104 + k0];
                for (int kk = 0; kk < 4; ++kk) w[kk] = *(const float4*)&Wh2[(k0 + kk) * 100 + c0];
                for (int kk = 0; kk < 4; ++kk)
                    for (int r = 0; r < 4; ++r) {
                        float as = (&a[r].x)[kk];
                        acc2[r][0] = fmaf(as, w[kk].x, acc2[r][0]);
                        acc2[r][1] = fmaf(as, w[kk].y, acc2[r][1]);
                        acc2[r][2] = fmaf(as, w[kk].z, acc2[r][2]);
                        acc2[r][3] = fmaf(as, w[kk].w, acc2[r][3]);
                    }
            }
            for (int r = 0; r < 4; ++r)
                for (int j = 0; j < 4; ++j) buf0[(r0 + r) * 124 + c0 + j] = gelu_f(acc2[r][j]);
        }
    }
    __syncthreads();
    {   // Wo1: K=120 from A2 -> gelu -> buf1
        float acc3[4][4];
        for (int r = 0; r < 4; ++r)
            for (int j = 0; j < 4; ++j) acc3[r][j] = valid ? bo1[c0 + j] : 0.f;
        if (valid) {
            for (int k0 = 0; k0 < 120; k0 += 4) {
                float4 a[4], w[4];
                for (int r = 0; r < 4; ++r) a[r] = *(const float4*)&buf0[(r0 + r) * 124 + k0];
                for (int kk = 0; kk < 4; ++kk) w[kk] = *(const float4*)&Wo1[(k0 + kk) * 100 + c0];
                for (int kk = 0; kk < 4; ++kk)
                    for (int r = 0; r < 4; ++r) {
                        float as = (&a[r].x)[kk];
                        acc3[r][0] = fmaf(as, w[kk].x, acc3[r][0]);
                        acc3[r][1] = fmaf(as, w[kk].y, acc3[r][1]);
                        acc3[r][2] = fmaf(as, w[kk].z, acc3[r][2]);
                        acc3[r][3] = fmaf(as, w[kk].w, acc3[r][3]);
                    }
            }
        }
        __syncthreads();
        if (valid)
            for (int r = 0; r < 4; ++r)
                for (int j = 0; j < 4; ++j) buf1[(r0 + r) * 104 + c0 + j] = gelu_f(acc3[r][j]);
    }
    __syncthreads();
    {   // Wo2: K=100 from buf1 -> gelu -> A2 cols 0..99
        float acc4[4][4];
        for (int r = 0; r < 4; ++r)
            for (int j = 0; j < 4; ++j) acc4[r][j] = valid ? bo2[c0 + j] : 0.f;
        if (valid) {
            for (int k0 = 0; k0 < 100; k0 += 4) {
                float4 a[4], w[4];
                for (int r = 0; r < 4; ++r) a[r] = *(const float4*)&buf1[(r0 + r) * 104 + k0];
                for (int kk = 0; kk < 4; ++kk) w[kk] = *(const float4*)&Wo2[(k0 + kk) * 100 + c0];
                for (int kk = 0; kk < 4; ++kk)
                    for (int r = 0; r < 4; ++r) {
                        float as = (&a[r].x)[kk];
                        acc4[r][0] = fmaf(as, w[kk].x, acc4[r][0]);
                        acc4[r][1] = fmaf(as, w[kk].y, acc4[r][1]);
                        acc4[r][2] = fmaf(as, w[kk].z, acc4[r][2]);
                        acc4[r][3] = fmaf(as, w[kk].w, acc4[r][3]);
                    }
            }
        }
        __syncthreads();
        if (valid)
            for (int r = 0; r < 4; ++r)
                for (int j = 0; j < 4; ++j) buf0[(r0 + r) * 124 + c0 + j] = gelu_f(acc4[r][j]);
    }
    __syncthreads();
    {   // Wo3: K=100 from A2 -> tanh -> xf [N,32]; 1 row per 8-thread group
        int c0b = (tid & 7) * 4, row = tid >> 3;
        float acc5[4];
        for (int j = 0; j < 4; ++j) acc5[j] = bo3[c0b + j];
        for (int k0 = 0; k0 < 100; k0 += 4) {
            float4 a = *(const float4*)&buf0[row * 124 + k0];
            float4 w[4];
            for (int kk = 0; kk < 4; ++kk) w[kk] = *(const float4*)&Wo3[(k0 + kk) * 32 + c0b];
            for (int kk = 0; kk < 4; ++kk) {
                float as = (&a.x)[kk];
                acc5[0] = fmaf(as, w[kk].x, acc5[0]);
                acc5[1] = fmaf(as, w[kk].y, acc5[1]);
                acc5[2] = fmaf(as, w[kk].z, acc5[2]);
                acc5[3] = fmaf(as, w[kk].w, acc5[3]);
            }
        }
        int gr = base + row;
        if (gr < N_) {
            float4 v = make_float4(tanhf(acc5[0]), tanhf(acc5[1]), tanhf(acc5[2]), tanhf(acc5[3]));
            *(float4*)&xf[(long)gr * 32 + c0b] = v;
        }
    }
}

// ---------------- VQ: 1 thread per node, codebook in LDS ----------------
__global__ __launch_bounds__(256) void k_vq(const float* __restrict__ xf,
    const float* __restrict__ cb, float* __restrict__ zq, float* __restrict__ loss) {
    __shared__ float CB[128 * 32];
    __shared__ float CC[128];
    __shared__ float SR[256];
    int tid = threadIdx.x;
    for (int i = 0; i < 4; ++i) {
        int f4 = i * 256 + tid;
        *(float4*)&CB[f4 * 4] = *(const float4*)&cb[f4 * 4];
    }
    __syncthreads();
    if (tid < 128) {
        float s = 0.f;
        for (int j = 0; j < 32; ++j) { float v = CB[tid * 32 + j]; s += v * v; }
        CC[tid] = s;
    }
    __syncthreads();
    int node = blockIdx.x * 256 + tid;
    float part = 0.f;
    if (node < N_) {
        float4 xv[8];
        for (int j4 = 0; j4 < 8; ++j4) xv[j4] = *(const float4*)&xf[(long)node * 32 + j4 * 4];
        float xx = 0.f;
        for (int j4 = 0; j4 < 8; ++j4)
            xx += xv[j4].x * xv[j4].x + xv[j4].y * xv[j4].y + xv[j4].z * xv[j4].z + xv[j4].w * xv[j4].w;
        float best = 3.4e38f;
        int bidx = 0;
        for (int k = 0; k < 128; ++k) {
            const float* cbr = &CB[k * 32];
            float dot = 0.f;
            for (int j4 = 0; j4 < 8; ++j4) {
                float4 cv = *(const float4*)&cbr[j4 * 4];
                dot += cv.x * xv[j4].x + cv.y * xv[j4].y + cv.z * xv[j4].z + cv.w * xv[j4].w;
            }
            float d = fmaf(-2.0f, dot, xx) + CC[k];
            if (d < best) { best = d; bidx = k; }
        }
        const float* q = &CB[bidx * 32];
        for (int j4 = 0; j4 < 8; ++j4) {
            float4 qv = *(const float4*)&q[j4 * 4];
            *(float4*)&zq[(long)node * 32 + j4 * 4] = qv;
            float4 xvv = xv[j4];
            float d0 = qv.x - xvv.x, d1 = qv.y - xvv.y, d2 = qv.z - xvv.z, d3 = qv.w - xvv.w;
            part += d0 * d0 + d1 * d1 + d2 * d2 + d3 * d3;
        }
    }
    SR[tid] = part;
    __syncthreads();
    for (int off = 128; off > 0; off >>= 1) {
        if (tid < off) SR[tid] += SR[tid + off];
        __syncthreads();
    }
    if (tid == 0) atomicAdd(loss, SR[0]);
}

__global__ void k_fin(float* dout, const float* loss) {
    if (threadIdx.x == 0 && blockIdx.x == 0)
        dout[(long)N_ * 32] = 1.25f * (loss[0] / 1600000.0f);
}

extern "C" void kernel_launch(void* const* d_in, const int* in_sizes, int n_in,
                              void* d_out, int out_size, void* d_ws, size_t ws_size,
                              hipStream_t stream) {
    const float* x_res = (const float*)d_in[0];
    const float* x_AA  = (const float*)d_in[1];
    const int*   EI    = (const int*)d_in[2];
    const float* ln_g  = (const float*)d_in[3];
    const float* ln_b  = (const float*)d_in[4];
    const float* W1    = (const float*)d_in[5];
    const float* b1    = (const float*)d_in[6];
    const float* W2    = (const float*)d_in[7];
    const float* b2    = (const float*)d_in[8];
    const float* sWl   = (const float*)d_in[9];
    const float* sWr   = (const float*)d_in[10];
    const float* sb    = (const float*)d_in[11];
    const float* gnw   = (const float*)d_in[12];
    const float* gnb   = (const float*)d_in[13];
    const float* gns   = (const float*)d_in[14];
    const float* Wh1   = (const float*)d_in[15];
    const float* bh1   = (const float*)d_in[16];
    const float* Wh2   = (const float*)d_in[17];
    const float* bh2   = (const float*)d_in[18];
    const float* Wo1   = (const float*)d_in[19];
    const float* bo1   = (const float*)d_in[20];
    const float* Wo2   = (const float*)d_in[21];
    const float* bo2   = (const float*)d_in[22];
    const float* Wo3   = (const float*)d_in[23];
    const float* bo3   = (const float*)d_in[24];
    const float* cbk   = (const float*)d_in[25];
    float* out = (float*)d_out;

    float* ws    = (float*)d_ws;
    float* xsave = ws;                               // N*384 (raw g per layer slice)
    float* x0    = xsave + (size_t)N_ * 384;         // N*128 (later reused as xf)
    float* agg   = x0 + (size_t)N_ * 128;            // 3*N*128
    float* wls   = agg + (size_t)3 * N_ * 128;       // 147456
    float* wra   = wls + 147456;                     // 49152
    float* ba    = wra + 49152;                      // 384
    float* idA   = ba + 384;                         // 128
    float* idB   = idA + 128;                        // 128
    float* normA = idB + 128;                        // 3*128
    float* normB = normA + 384;                      // 3*128
    // zero-init region: [cursor 1][loss 1][cs 3*128][cq 3*128]
    int*   cursor = (int*)(normB + 384);             // 1
    float* loss  = (float*)(cursor + 1);             // 1
    float* cs    = loss + 1;                         // 3*128
    float* cq    = cs + 384;                         // 3*128
    int*   head  = (int*)(cq + 384);                 // NG_  (memset 0xFF)
    int*   nxt   = head + NG_;                       // T_*E_
    int*   cnt   = nxt + (size_t)T_ * E_;            // NG_
    int*   rpA   = cnt + NG_;                        // NG_
    float* inv   = (float*)(rpA + NG_);              // NG_
    int*   csr   = (int*)(inv + NG_);                // T_*E_
    float* xf    = x0;                               // reuse x0 (dead after layer 0)

    hipMemsetAsync(cursor, 0, 770 * sizeof(int), stream);
    hipMemsetAsync(head, 0xFF, NG_ * sizeof(int), stream);

    k_prep<<<576, 256, 0, stream>>>(sWl, sWr, sb, wls, wra, ba, idA, idB);
    k_link<<<(T_ * E_ + 255) / 256, 256, 0, stream>>>(EI, head, nxt);
    k_compact<<<(NG_ + 255) / 256, 256, 0, stream>>>(EI, head, nxt, cursor, cnt, rpA, inv, csr);
    k_inmlp<<<(N_ + 31) / 32, 256, 0, stream>>>(x_res, ln_g, ln_b, W1, b1, W2, b2, x0);

    for (int l = 0; l < 3; ++l) {
        const float* X = (l == 0) ? x0 : (xsave + (size_t)(l - 1) * 128);
        int ldx = (l == 0) ? 128 : 384;
        const float* nAl = (l == 0) ? idA : (normA + (size_t)(l - 1) * 128);
        const float* nBl = (l == 0) ? idB : (normB + (size_t)(l - 1) * 128);
        k_gather<<<NG_ / 4, 256, 0, stream>>>(rpA, cnt, csr, inv, X, ldx, nAl, nBl, agg);
        k_gemm_body<<<(N_ + 63) / 64, 256, 0, stream>>>(X, ldx, agg, nAl, nBl,
            wls + (size_t)l * 3 * 16384, wra + (size_t)l * 16384, ba + l * 128,
            xsave + (size_t)l * 128, cs + l * 128, cq + l * 128);
        k_norm<<<1, 128, 0, stream>>>(cs + l * 128, cq + l * 128, gns + l * 128,
                                      gnw + l * 128, gnb + l * 128,
                                      normA + (size_t)l * 128, normB + (size_t)l * 128);
    }
    k_head<<<(N_ + 31) / 32, 256, 0, stream>>>(xsave, normA, normB, Wh1, bh1, Wh2, bh2,
                                               x_AA, Wo1, bo1, Wo2, bo2, Wo3, bo3, xf);
    k_vq<<<(N_ + 255) / 256, 256, 0, stream>>>(xf, cbk, out, loss);
    k_fin<<<1, 64, 0, stream>>>(out, loss);
}

// Round 11
// 1418.923 us; speedup vs baseline: 1.4648x; 1.4612x over previous
//
#include <hip/hip_runtime.h>

#define N_ 50000
#define E_ 800000
#define T_ 3
#define NG_ (T_ * N_)   // 150000 (type,dst) groups
#define EPS_ 1e-5f

__device__ __forceinline__ float gelu_f(float x) {
    return 0.5f * x * (1.0f + erff(x * 0.70710678118654752440f));
}

// ---------------- weight prep: Wl/3, mean(Wr), mean(b), identity norm ----------------
__global__ void k_prep(const float* __restrict__ Wl, const float* __restrict__ Wr,
                       const float* __restrict__ b, float* wls, float* wra, float* ba,
                       float* idA, float* idB) {
    int i = blockIdx.x * 256 + threadIdx.x;
    const float third = 1.0f / 3.0f;
    if (i < 9 * 128 * 128) wls[i] = Wl[i] * third;
    if (i < 3 * 128 * 128) {
        int l = i >> 14, rem = i & 16383;
        const float* p = Wr + l * 3 * 16384 + rem;
        wra[i] = (p[0] + p[16384] + p[32768]) * third;
    }
    if (i < 3 * 128) {
        int l = i >> 7, c = i & 127;
        const float* p = b + l * 3 * 128 + c;
        ba[i] = (p[0] + p[128] + p[256]) * third;
    }
    if (i < 128) { idA[i] = 1.0f; idB[i] = 0.0f; }
}

// ---------------- linked-list build: head[g] -> chain of global edge ids ----------------
__global__ void k_link(const int* __restrict__ EI, int* __restrict__ head, int* __restrict__ nxt) {
    int i = blockIdx.x * 256 + threadIdx.x;
    if (i >= T_ * E_) return;
    int t = i / E_, e = i - t * E_;
    int d = EI[(t * 2 + 1) * E_ + e];
    nxt[i] = atomicExch(&head[t * N_ + d], i);
}

// ---- compact lists -> csr segments; cnt/inv; wave-scanned cursor allocation ----
__global__ __launch_bounds__(256) void k_compact(
    const int* __restrict__ EI, const int* __restrict__ head, const int* __restrict__ nxt,
    int* __restrict__ cursor, int* __restrict__ cnt, int* __restrict__ rpA,
    float* __restrict__ inv, int* __restrict__ csr) {
    int tid = threadIdx.x;
    int g = blockIdx.x * 256 + tid;
    bool ok = (g < NG_);
    int lane = tid & 63;
    int c = 0;
    int h = -1;
    if (ok) {
        h = head[g];
        int e = h;
        while (e >= 0) { c++; e = nxt[e]; }
        cnt[g] = c;
        inv[g] = 1.0f / (float)(c > 0 ? c : 1);
    }
    int x = c;
    for (int off = 1; off < 64; off <<= 1) {
        int y = __shfl_up(x, off);
        if (lane >= off) x += y;
    }
    int total = __shfl(x, 63);
    int base = 0;
    if (lane == 63 && total > 0) base = atomicAdd(cursor, total);
    base = __shfl(base, 63);
    if (ok) {
        int pos = base + x - c;
        rpA[g] = pos;
        int e = h;
        while (e >= 0) {
            int t = e / E_, idx = e - t * E_;
            csr[pos++] = EI[(t * 2) * E_ + idx];
            e = nxt[e];
        }
    }
}

// ---------------- input LN + MLP (64 -> 256 -> 128) ----------------
__global__ __launch_bounds__(256) void k_inmlp(
    const float* __restrict__ xres, const float* __restrict__ gam, const float* __restrict__ bet,
    const float* __restrict__ W1, const float* __restrict__ b1,
    const float* __restrict__ W2, const float* __restrict__ b2, float* __restrict__ x0) {
    __shared__ float xr[32][68];
    __shared__ float h1[32][260];
    int tid = threadIdx.x;
    int base = blockIdx.x * 32;
    for (int i = 0; i < 2; ++i) {
        int f4 = i * 256 + tid;
        int r = f4 >> 4, c4 = f4 & 15;
        float4 v = make_float4(0.f, 0.f, 0.f, 0.f);
        int gr = base + r;
        if (gr < N_) v = *(const float4*)&xres[gr * 64 + c4 * 4];
        *(float4*)&xr[r][c4 * 4] = v;
    }
    __syncthreads();
    {   // LayerNorm: 8 lanes per row
        int r = tid >> 3, l8 = tid & 7;
        float s = 0.f;
        for (int k = l8; k < 64; k += 8) s += xr[r][k];
        s += __shfl_xor(s, 1); s += __shfl_xor(s, 2); s += __shfl_xor(s, 4);
        float mu = s * (1.0f / 64.0f);
        float v = 0.f;
        for (int k = l8; k < 64; k += 8) { float d = xr[r][k] - mu; v += d * d; }
        v += __shfl_xor(v, 1); v += __shfl_xor(v, 2); v += __shfl_xor(v, 4);
        float rs = rsqrtf(v * (1.0f / 64.0f) + EPS_);
        for (int k = l8; k < 64; k += 8)
            xr[r][k] = (xr[r][k] - mu) * rs * gam[k] + bet[k];
    }
    __syncthreads();
    {   // GEMM1 [32x64]@[64x256] -> gelu -> h1
        int tx = tid & 63, ty = tid >> 6;
        int c0 = tx * 4, r0 = ty * 8;
        float acc[8][4];
        for (int r = 0; r < 8; ++r)
            for (int j = 0; j < 4; ++j) acc[r][j] = b1[c0 + j];
        for (int k0 = 0; k0 < 64; k0 += 4) {
            float4 a[8], w[4];
            for (int r = 0; r < 8; ++r) a[r] = *(const float4*)&xr[r0 + r][k0];
            for (int kk = 0; kk < 4; ++kk) w[kk] = *(const float4*)&W1[(k0 + kk) * 256 + c0];
            for (int kk = 0; kk < 4; ++kk)
                for (int r = 0; r < 8; ++r) {
                    float as = (&a[r].x)[kk];
                    acc[r][0] = fmaf(as, w[kk].x, acc[r][0]);
                    acc[r][1] = fmaf(as, w[kk].y, acc[r][1]);
                    acc[r][2] = fmaf(as, w[kk].z, acc[r][2]);
                    acc[r][3] = fmaf(as, w[kk].w, acc[r][3]);
                }
        }
        for (int r = 0; r < 8; ++r)
            for (int j = 0; j < 4; ++j) h1[r0 + r][c0 + j] = gelu_f(acc[r][j]);
    }
    __syncthreads();
    {   // GEMM2 [32x256]@[256x128] -> gelu -> x0
        int tx = tid & 31, ty = tid >> 5;
        int c0 = tx * 4, r0 = ty * 4;
        float acc[4][4];
        for (int r = 0; r < 4; ++r)
            for (int j = 0; j < 4; ++j) acc[r][j] = b2[c0 + j];
        for (int k0 = 0; k0 < 256; k0 += 4) {
            float4 a[4], w[4];
            for (int r = 0; r < 4; ++r) a[r] = *(const float4*)&h1[r0 + r][k0];
            for (int kk = 0; kk < 4; ++kk) w[kk] = *(const float4*)&W2[(k0 + kk) * 128 + c0];
            for (int kk = 0; kk < 4; ++kk)
                for (int r = 0; r < 4; ++r) {
                    float as = (&a[r].x)[kk];
                    acc[r][0] = fmaf(as, w[kk].x, acc[r][0]);
                    acc[r][1] = fmaf(as, w[kk].y, acc[r][1]);
                    acc[r][2] = fmaf(as, w[kk].z, acc[r][2]);
                    acc[r][3] = fmaf(as, w[kk].w, acc[r][3]);
                }
        }
        for (int r = 0; r < 4; ++r) {
            int gr = base + r0 + r;
            if (gr < N_) {
                float4 v = make_float4(gelu_f(acc[r][0]), gelu_f(acc[r][1]),
                                       gelu_f(acc[r][2]), gelu_f(acc[r][3]));
                *(float4*)&x0[(long)gr * 128 + c0] = v;
            }
        }
    }
}

// ---- CSR gather: agg[g] = norm-affine(inv * sum_{src} X[src]) ----
__global__ __launch_bounds__(256) void k_gather(
    const int* __restrict__ rpA, const int* __restrict__ cnt, const int* __restrict__ csr,
    const float* __restrict__ inv, const float* __restrict__ X, int ldx,
    const float* __restrict__ nA, const float* __restrict__ nB, float* __restrict__ agg) {
    int tid = threadIdx.x;
    int g = blockIdx.x * 4 + (tid >> 6);
    if (g >= NG_) return;
    int lane = tid & 63;
    int sub = lane >> 4;
    int f = (lane & 15) * 8;
    int start = rpA[g];
    int end = start + cnt[g];
    float4 s0 = make_float4(0.f, 0.f, 0.f, 0.f);
    float4 s1 = make_float4(0.f, 0.f, 0.f, 0.f);
    for (int e = start + sub; e < end; e += 4) {
        int sn = csr[e];
        const float* row = &X[(long)sn * ldx + f];
        const float4 v0 = *(const float4*)row;
        const float4 v1 = *(const float4*)(row + 4);
        s0.x += v0.x; s0.y += v0.y; s0.z += v0.z; s0.w += v0.w;
        s1.x += v1.x; s1.y += v1.y; s1.z += v1.z; s1.w += v1.w;
    }
    s0.x += __shfl_xor(s0.x, 16); s0.y += __shfl_xor(s0.y, 16);
    s0.z += __shfl_xor(s0.z, 16); s0.w += __shfl_xor(s0.w, 16);
    s1.x += __shfl_xor(s1.x, 16); s1.y += __shfl_xor(s1.y, 16);
    s1.z += __shfl_xor(s1.z, 16); s1.w += __shfl_xor(s1.w, 16);
    s0.x += __shfl_xor(s0.x, 32); s0.y += __shfl_xor(s0.y, 32);
    s0.z += __shfl_xor(s0.z, 32); s0.w += __shfl_xor(s0.w, 32);
    s1.x += __shfl_xor(s1.x, 32); s1.y += __shfl_xor(s1.y, 32);
    s1.z += __shfl_xor(s1.z, 32); s1.w += __shfl_xor(s1.w, 32);
    if (sub == 0) {
        float iv = inv[g];
        float bsel = (end > start) ? 1.0f : 0.0f;
        float4 A0 = *(const float4*)&nA[f];
        float4 A1 = *(const float4*)&nA[f + 4];
        float4 B0 = *(const float4*)&nB[f];
        float4 B1 = *(const float4*)&nB[f + 4];
        float* op = &agg[(long)g * 128 + f];
        *(float4*)op = make_float4(fmaf(s0.x * iv, A0.x, bsel * B0.x),
                                   fmaf(s0.y * iv, A0.y, bsel * B0.y),
                                   fmaf(s0.z * iv, A0.z, bsel * B0.z),
                                   fmaf(s0.w * iv, A0.w, bsel * B0.w));
        *(float4*)(op + 4) = make_float4(fmaf(s1.x * iv, A1.x, bsel * B1.x),
                                         fmaf(s1.y * iv, A1.y, bsel * B1.y),
                                         fmaf(s1.z * iv, A1.z, bsel * B1.z),
                                         fmaf(s1.w * iv, A1.w, bsel * B1.w));
    }
}

// ---- body GEMM: g = gelu(sum_t agg_t@(Wl_t/3) + norm(x)@Wr_avg + b_avg);
//      writes RAW g into xsave slice; accumulates colsum(g), colsum(g^2) ----
__global__ __launch_bounds__(256) void k_gemm_body(
    const float* __restrict__ X, int ldx, const float* __restrict__ agg,
    const float* __restrict__ nA, const float* __restrict__ nB,
    const float* __restrict__ wls_l, const float* __restrict__ wra_l, const float* __restrict__ ba_l,
    float* __restrict__ xsl, float* __restrict__ cs_l, float* __restrict__ cq_l) {
    __shared__ float xs[64][132];
    __shared__ float sd[8][128];
    __shared__ float sq[8][128];
    __shared__ float nAs[128], nBs[128];
    int tid = threadIdx.x;
    int base = blockIdx.x * 64;
    if (tid < 128) { nAs[tid] = nA[tid]; nBs[tid] = nB[tid]; }
    int tx = tid & 31, ty = tid >> 5;
    int c0 = tx * 4, r0 = ty * 8;
    float acc[8][4];
    for (int r = 0; r < 8; ++r)
        for (int j = 0; j < 4; ++j) acc[r][j] = ba_l[c0 + j];
    for (int seg = 0; seg < 4; ++seg) {
        const float* src; long ld;
        if (seg < 3) { src = agg + ((long)seg * N_ + base) * 128; ld = 128; }
        else         { src = X + (long)base * ldx; ld = ldx; }
        __syncthreads();
        for (int i = 0; i < 8; ++i) {
            int f4 = i * 256 + tid;
            int r = f4 >> 5, c4 = f4 & 31;
            float4 v = make_float4(0.f, 0.f, 0.f, 0.f);
            if (base + r < N_) v = *(const float4*)&src[(long)r * ld + c4 * 4];
            if (seg == 3) {
                int cc = c4 * 4;
                v.x = fmaf(v.x, nAs[cc], nBs[cc]);
                v.y = fmaf(v.y, nAs[cc + 1], nBs[cc + 1]);
                v.z = fmaf(v.z, nAs[cc + 2], nBs[cc + 2]);
                v.w = fmaf(v.w, nAs[cc + 3], nBs[cc + 3]);
            }
            *(float4*)&xs[r][c4 * 4] = v;
        }
        __syncthreads();
        const float* W = (seg < 3) ? (wls_l + seg * 16384) : wra_l;
        for (int k0 = 0; k0 < 128; k0 += 4) {
            float4 a[8], w[4];
            for (int r = 0; r < 8; ++r) a[r] = *(const float4*)&xs[r0 + r][k0];
            for (int kk = 0; kk < 4; ++kk) w[kk] = *(const float4*)&W[(k0 + kk) * 128 + c0];
            for (int kk = 0; kk < 4; ++kk)
                for (int r = 0; r < 8; ++r) {
                    float as = (&a[r].x)[kk];
                    acc[r][0] = fmaf(as, w[kk].x, acc[r][0]);
                    acc[r][1] = fmaf(as, w[kk].y, acc[r][1]);
                    acc[r][2] = fmaf(as, w[kk].z, acc[r][2]);
                    acc[r][3] = fmaf(as, w[kk].w, acc[r][3]);
                }
        }
    }
    float csum[4] = {0.f, 0.f, 0.f, 0.f};
    float qsum[4] = {0.f, 0.f, 0.f, 0.f};
    for (int r = 0; r < 8; ++r) {
        int gr = base + r0 + r;
        if (gr < N_) {
            float g0 = gelu_f(acc[r][0]), g1 = gelu_f(acc[r][1]);
            float g2 = gelu_f(acc[r][2]), g3 = gelu_f(acc[r][3]);
            *(float4*)&xsl[(long)gr * 384 + c0] = make_float4(g0, g1, g2, g3);
            csum[0] += g0; csum[1] += g1; csum[2] += g2; csum[3] += g3;
            qsum[0] += g0 * g0; qsum[1] += g1 * g1; qsum[2] += g2 * g2; qsum[3] += g3 * g3;
        }
    }
    *(float4*)&sd[ty][c0] = make_float4(csum[0], csum[1], csum[2], csum[3]);
    *(float4*)&sq[ty][c0] = make_float4(qsum[0], qsum[1], qsum[2], qsum[3]);
    __syncthreads();
    if (tid < 128) {
        float t = 0.f, q = 0.f;
        for (int i = 0; i < 8; ++i) { t += sd[i][tid]; q += sq[i][tid]; }
        atomicAdd(&cs_l[tid], t);
        atomicAdd(&cq_l[tid], q);
    }
}

// ---------------- norm coefficients: nA = rsqrt(var+eps)*gw, nB = gb - sm*nA ----------------
__global__ void k_norm(const float* __restrict__ cs_l, const float* __restrict__ cq_l,
                       const float* __restrict__ gsc, const float* __restrict__ gw,
                       const float* __restrict__ gb, float* __restrict__ nA, float* __restrict__ nB) {
    int c = threadIdx.x;
    float mu = cs_l[c] / 50000.0f;
    float sm = gsc[c] * mu;
    float var = cq_l[c] / 50000.0f - 2.0f * sm * mu + sm * sm;
    float a = rsqrtf(var + EPS_) * gw[c];
    nA[c] = a;
    nB[c] = gb[c] - sm * a;
}

// ---- fused head (round-7 shape) + VQ tail: norm(xsave)@Wh1..@Wo3 tanh -> VQ -> zq, loss ----
__global__ __launch_bounds__(256) void k_head(const float* __restrict__ xsave,
    const float* __restrict__ nA, const float* __restrict__ nB,
    const float* __restrict__ Wh1, const float* __restrict__ bh1,
    const float* __restrict__ Wh2, const float* __restrict__ bh2,
    const float* __restrict__ xAA,
    const float* __restrict__ Wo1, const float* __restrict__ bo1,
    const float* __restrict__ Wo2, const float* __restrict__ bo2,
    const float* __restrict__ Wo3, const float* __restrict__ bo3,
    const float* __restrict__ cb, float* __restrict__ zq, float* __restrict__ loss) {
    __shared__ __align__(16) float buf0[64 * 124];   // at-tile / A2; later CB(128x36)+CC+SR
    __shared__ __align__(16) float buf1[64 * 104];   // h1b / B2; later XF(64x36)
    __shared__ float nAs[384], nBs[384];
    int tid = threadIdx.x;
    int base = blockIdx.x * 64;
    for (int i = tid; i < 384; i += 256) { nAs[i] = nA[i]; nBs[i] = nB[i]; }
    int tx = tid & 31, ty = tid >> 5;
    int c0 = tx * 4, r0 = ty * 8;
    bool valid = (c0 < 100);
    float acc[8][4];
    for (int r = 0; r < 8; ++r)
        for (int j = 0; j < 4; ++j) acc[r][j] = valid ? bh1[c0 + j] : 0.f;
    for (int kt = 0; kt < 6; ++kt) {
        __syncthreads();
        for (int i = 0; i < 2; ++i) {
            int f4 = i * 256 + tid;
            int r = f4 >> 4, c4 = f4 & 15;
            int col = kt * 64 + c4 * 4;
            float4 v = make_float4(0.f, 0.f, 0.f, 0.f);
            int gr = base + r;
            if (gr < N_) v = *(const float4*)&xsave[(long)gr * 384 + col];
            v.x = fmaf(v.x, nAs[col], nBs[col]);
            v.y = fmaf(v.y, nAs[col + 1], nBs[col + 1]);
            v.z = fmaf(v.z, nAs[col + 2], nBs[col + 2]);
            v.w = fmaf(v.w, nAs[col + 3], nBs[col + 3]);
            *(float4*)&buf0[r * 68 + c4 * 4] = v;
        }
        __syncthreads();
        if (valid) {
            for (int k0 = 0; k0 < 64; k0 += 4) {
                float4 a[8], w[4];
                for (int r = 0; r < 8; ++r) a[r] = *(const float4*)&buf0[(r0 + r) * 68 + k0];
                for (int kk = 0; kk < 4; ++kk) w[kk] = *(const float4*)&Wh1[(kt * 64 + k0 + kk) * 100 + c0];
                for (int kk = 0; kk < 4; ++kk)
                    for (int r = 0; r < 8; ++r) {
                        float as = (&a[r].x)[kk];
                        acc[r][0] = fmaf(as, w[kk].x, acc[r][0]);
                        acc[r][1] = fmaf(as, w[kk].y, acc[r][1]);
                        acc[r][2] = fmaf(as, w[kk].z, acc[r][2]);
                        acc[r][3] = fmaf(as, w[kk].w, acc[r][3]);
                    }
            }
        }
    }
    __syncthreads();
    if (valid)
        for (int r = 0; r < 8; ++r)
            for (int j = 0; j < 4; ++j) buf1[(r0 + r) * 104 + c0 + j] = gelu_f(acc[r][j]);
    __syncthreads();
    // stage xAA into A2 cols 100..119 (buf0 now A2 layout, stride 124)
    for (int i = 0; i < 2; ++i) {
        int f4 = i * 256 + tid;
        if (f4 < 320) {
            int r = f4 / 5, c4 = f4 - r * 5;
            float4 v = make_float4(0.f, 0.f, 0.f, 0.f);
            int gr = base + r;
            if (gr < N_) v = *(const float4*)&xAA[(long)gr * 20 + c4 * 4];
            *(float4*)&buf0[r * 124 + 100 + c4 * 4] = v;
        }
    }
    {   // Wh2: K=100 from buf1 -> gelu -> A2 cols 0..99
        float acc2[8][4];
        for (int r = 0; r < 8; ++r)
            for (int j = 0; j < 4; ++j) acc2[r][j] = valid ? bh2[c0 + j] : 0.f;
        if (valid) {
            for (int k0 = 0; k0 < 100; k0 += 4) {
                float4 a[8], w[4];
                for (int r = 0; r < 8; ++r) a[r] = *(const float4*)&buf1[(r0 + r) * 104 + k0];
                for (int kk = 0; kk < 4; ++kk) w[kk] = *(const float4*)&Wh2[(k0 + kk) * 100 + c0];
                for (int kk = 0; kk < 4; ++kk)
                    for (int r = 0; r < 8; ++r) {
                        float as = (&a[r].x)[kk];
                        acc2[r][0] = fmaf(as, w[kk].x, acc2[r][0]);
                        acc2[r][1] = fmaf(as, w[kk].y, acc2[r][1]);
                        acc2[r][2] = fmaf(as, w[kk].z, acc2[r][2]);
                        acc2[r][3] = fmaf(as, w[kk].w, acc2[r][3]);
                    }
            }
            for (int r = 0; r < 8; ++r)
                for (int j = 0; j < 4; ++j) buf0[(r0 + r) * 124 + c0 + j] = gelu_f(acc2[r][j]);
        }
    }
    __syncthreads();
    {   // Wo1: K=120 from A2 -> gelu -> buf1
        float acc3[8][4];
        for (int r = 0; r < 8; ++r)
            for (int j = 0; j < 4; ++j) acc3[r][j] = valid ? bo1[c0 + j] : 0.f;
        if (valid) {
            for (int k0 = 0; k0 < 120; k0 += 4) {
                float4 a[8], w[4];
                for (int r = 0; r < 8; ++r) a[r] = *(const float4*)&buf0[(r0 + r) * 124 + k0];
                for (int kk = 0; kk < 4; ++kk) w[kk] = *(const float4*)&Wo1[(k0 + kk) * 100 + c0];
                for (int kk = 0; kk < 4; ++kk)
                    for (int r = 0; r < 8; ++r) {
                        float as = (&a[r].x)[kk];
                        acc3[r][0] = fmaf(as, w[kk].x, acc3[r][0]);
                        acc3[r][1] = fmaf(as, w[kk].y, acc3[r][1]);
                        acc3[r][2] = fmaf(as, w[kk].z, acc3[r][2]);
                        acc3[r][3] = fmaf(as, w[kk].w, acc3[r][3]);
                    }
            }
        }
        __syncthreads();
        if (valid)
            for (int r = 0; r < 8; ++r)
                for (int j = 0; j < 4; ++j) buf1[(r0 + r) * 104 + c0 + j] = gelu_f(acc3[r][j]);
    }
    __syncthreads();
    {   // Wo2: K=100 from buf1 -> gelu -> A2 cols 0..99
        float acc4[8][4];
        for (int r = 0; r < 8; ++r)
            for (int j = 0; j < 4; ++j) acc4[r][j] = valid ? bo2[c0 + j] : 0.f;
        if (valid) {
            for (int k0 = 0; k0 < 100; k0 += 4) {
                float4 a[8], w[4];
                for (int r = 0; r < 8; ++r) a[r] = *(const float4*)&buf1[(r0 + r) * 104 + k0];
                for (int kk = 0; kk < 4; ++kk) w[kk] = *(const float4*)&Wo2[(k0 + kk) * 100 + c0];
                for (int kk = 0; kk < 4; ++kk)
                    for (int r = 0; r < 8; ++r) {
                        float as = (&a[r].x)[kk];
                        acc4[r][0] = fmaf(as, w[kk].x, acc4[r][0]);
                        acc4[r][1] = fmaf(as, w[kk].y, acc4[r][1]);
                        acc4[r][2] = fmaf(as, w[kk].z, acc4[r][2]);
                        acc4[r][3] = fmaf(as, w[kk].w, acc4[r][3]);
                    }
            }
        }
        __syncthreads();
        if (valid)
            for (int r = 0; r < 8; ++r)
                for (int j = 0; j < 4; ++j) buf0[(r0 + r) * 124 + c0 + j] = gelu_f(acc4[r][j]);
    }
    __syncthreads();
    {   // Wo3: K=100 from A2 -> tanh -> XF staged into buf1 (stride 36)
        int c0b = (tid & 7) * 4, rg = tid >> 3;
        int r0b = rg * 2;
        float acc5[2][4];
        for (int r = 0; r < 2; ++r)
            for (int j = 0; j < 4; ++j) acc5[r][j] = bo3[c0b + j];
        for (int k0 = 0; k0 < 100; k0 += 4) {
            float4 a[2], w[4];
            for (int r = 0; r < 2; ++r) a[r] = *(const float4*)&buf0[(r0b + r) * 124 + k0];
            for (int kk = 0; kk < 4; ++kk) w[kk] = *(const float4*)&Wo3[(k0 + kk) * 32 + c0b];
            for (int kk = 0; kk < 4; ++kk)
                for (int r = 0; r < 2; ++r) {
                    float as = (&a[r].x)[kk];
                    acc5[r][0] = fmaf(as, w[kk].x, acc5[r][0]);
                    acc5[r][1] = fmaf(as, w[kk].y, acc5[r][1]);
                    acc5[r][2] = fmaf(as, w[kk].z, acc5[r][2]);
                    acc5[r][3] = fmaf(as, w[kk].w, acc5[r][3]);
                }
        }
        // buf1 is free (Wo2 consumed it; sync above); stage XF there
        for (int r = 0; r < 2; ++r) {
            float4 v = make_float4(tanhf(acc5[r][0]), tanhf(acc5[r][1]),
                                   tanhf(acc5[r][2]), tanhf(acc5[r][3]));
            *(float4*)&buf1[(r0b + r) * 36 + c0b] = v;
        }
    }
    __syncthreads();   // all Wo3 reads of buf0 done; XF visible
    // load codebook into buf0: CB[k*36 + j], k=0..127; CC at buf0+4608; SR at buf0+4736
    float* CB = buf0;
    float* CC = buf0 + 4608;
    float* SR = buf0 + 4736;
    for (int i = 0; i < 4; ++i) {
        int f4 = i * 256 + tid;       // 1024 float4s
        int k = f4 >> 3, j4 = f4 & 7;
        float4 v = *(const float4*)&cb[k * 32 + j4 * 4];
        *(float4*)&CB[k * 36 + j4 * 4] = v;
    }
    __syncthreads();
    if (tid < 128) {
        float s = 0.f;
        for (int j = 0; j < 32; ++j) { float v = CB[tid * 36 + j]; s += v * v; }
        CC[tid] = s;
    }
    __syncthreads();
    {   // VQ: 4 threads per node, 64 nodes, 32 codes each (k = kk*4+t4)
        int node = tid >> 2, t4 = tid & 3;
        float4 xv[8];
        for (int j4 = 0; j4 < 8; ++j4) xv[j4] = *(const float4*)&buf1[node * 36 + j4 * 4];
        float xx = 0.f;
        for (int j4 = 0; j4 < 8; ++j4)
            xx += xv[j4].x * xv[j4].x + xv[j4].y * xv[j4].y + xv[j4].z * xv[j4].z + xv[j4].w * xv[j4].w;
        float best = 3.4e38f;
        int bidx = 0;
        for (int kk = 0; kk < 32; ++kk) {
            int k = kk * 4 + t4;
            const float* cbr = &CB[k * 36];
            float dot = 0.f;
            for (int j4 = 0; j4 < 8; ++j4) {
                float4 cv = *(const float4*)&cbr[j4 * 4];
                dot += cv.x * xv[j4].x + cv.y * xv[j4].y + cv.z * xv[j4].z + cv.w * xv[j4].w;
            }
            float d = fmaf(-2.0f, dot, xx) + CC[k];
            if (d < best) { best = d; bidx = k; }
        }
        for (int off = 1; off < 4; off <<= 1) {
            float ob = __shfl_xor(best, off);
            int oi = __shfl_xor(bidx, off);
            if (ob < best || (ob == best && oi < bidx)) { best = ob; bidx = oi; }
        }
        int gr = base + node;
        if (t4 == 0) {
            float s = 0.f;
            if (gr < N_) {
                const float* q = &CB[bidx * 36];
                for (int j4 = 0; j4 < 8; ++j4) {
                    float4 qv = *(const float4*)&q[j4 * 4];
                    *(float4*)&zq[(long)gr * 32 + j4 * 4] = qv;
                    float4 xvv = xv[j4];
                    float d0 = qv.x - xvv.x, d1 = qv.y - xvv.y, d2 = qv.z - xvv.z, d3 = qv.w - xvv.w;
                    s += d0 * d0 + d1 * d1 + d2 * d2 + d3 * d3;
                }
            }
            SR[node] = s;
        }
    }
    __syncthreads();
    if (tid == 0) {
        float S = 0.f;
        for (int i = 0; i < 64; ++i) S += SR[i];
        atomicAdd(loss, S);
    }
}

__global__ void k_fin(float* dout, const float* loss) {
    if (threadIdx.x == 0 && blockIdx.x == 0)
        dout[(long)N_ * 32] = 1.25f * (loss[0] / 1600000.0f);
}

extern "C" void kernel_launch(void* const* d_in, const int* in_sizes, int n_in,
                              void* d_out, int out_size, void* d_ws, size_t ws_size,
                              hipStream_t stream) {
    const float* x_res = (const float*)d_in[0];
    const float* x_AA  = (const float*)d_in[1];
    const int*   EI    = (const int*)d_in[2];
    const float* ln_g  = (const float*)d_in[3];
    const float* ln_b  = (const float*)d_in[4];
    const float* W1    = (const float*)d_in[5];
    const float* b1    = (const float*)d_in[6];
    const float* W2    = (const float*)d_in[7];
    const float* b2    = (const float*)d_in[8];
    const float* sWl   = (const float*)d_in[9];
    const float* sWr   = (const float*)d_in[10];
    const float* sb    = (const float*)d_in[11];
    const float* gnw   = (const float*)d_in[12];
    const float* gnb   = (const float*)d_in[13];
    const float* gns   = (const float*)d_in[14];
    const float* Wh1   = (const float*)d_in[15];
    const float* bh1   = (const float*)d_in[16];
    const float* Wh2   = (const float*)d_in[17];
    const float* bh2   = (const float*)d_in[18];
    const float* Wo1   = (const float*)d_in[19];
    const float* bo1   = (const float*)d_in[20];
    const float* Wo2   = (const float*)d_in[21];
    const float* bo2   = (const float*)d_in[22];
    const float* Wo3   = (const float*)d_in[23];
    const float* bo3   = (const float*)d_in[24];
    const float* cbk   = (const float*)d_in[25];
    float* out = (float*)d_out;

    float* ws    = (float*)d_ws;
    float* xsave = ws;                               // N*384 (raw g per layer slice)
    float* x0    = xsave + (size_t)N_ * 384;         // N*128
    float* agg   = x0 + (size_t)N_ * 128;            // 3*N*128
    float* wls   = agg + (size_t)3 * N_ * 128;       // 147456
    float* wra   = wls + 147456;                     // 49152
    float* ba    = wra + 49152;                      // 384
    float* idA   = ba + 384;                         // 128
    float* idB   = idA + 128;                        // 128
    float* normA = idB + 128;                        // 3*128
    float* normB = normA + 384;                      // 3*128
    // zero-init region: [cursor 1][loss 1][cs 3*128][cq 3*128]
    int*   cursor = (int*)(normB + 384);             // 1
    float* loss  = (float*)(cursor + 1);             // 1
    float* cs    = loss + 1;                         // 3*128
    float* cq    = cs + 384;                         // 3*128
    int*   head  = (int*)(cq + 384);                 // NG_  (memset 0xFF)
    int*   nxt   = head + NG_;                       // T_*E_
    int*   cnt   = nxt + (size_t)T_ * E_;            // NG_
    int*   rpA   = cnt + NG_;                        // NG_
    float* inv   = (float*)(rpA + NG_);              // NG_
    int*   csr   = (int*)(inv + NG_);                // T_*E_

    hipMemsetAsync(cursor, 0, 770 * sizeof(int), stream);
    hipMemsetAsync(head, 0xFF, NG_ * sizeof(int), stream);

    k_prep<<<576, 256, 0, stream>>>(sWl, sWr, sb, wls, wra, ba, idA, idB);
    k_link<<<(T_ * E_ + 255) / 256, 256, 0, stream>>>(EI, head, nxt);
    k_compact<<<(NG_ + 255) / 256, 256, 0, stream>>>(EI, head, nxt, cursor, cnt, rpA, inv, csr);
    k_inmlp<<<(N_ + 31) / 32, 256, 0, stream>>>(x_res, ln_g, ln_b, W1, b1, W2, b2, x0);

    for (int l = 0; l < 3; ++l) {
        const float* X = (l == 0) ? x0 : (xsave + (size_t)(l - 1) * 128);
        int ldx = (l == 0) ? 128 : 384;
        const float* nAl = (l == 0) ? idA : (normA + (size_t)(l - 1) * 128);
        const float* nBl = (l == 0) ? idB : (normB + (size_t)(l - 1) * 128);
        k_gather<<<NG_ / 4, 256, 0, stream>>>(rpA, cnt, csr, inv, X, ldx, nAl, nBl, agg);
        k_gemm_body<<<(N_ + 63) / 64, 256, 0, stream>>>(X, ldx, agg, nAl, nBl,
            wls + (size_t)l * 3 * 16384, wra + (size_t)l * 16384, ba + l * 128,
            xsave + (size_t)l * 128, cs + l * 128, cq + l * 128);
        k_norm<<<1, 128, 0, stream>>>(cs + l * 128, cq + l * 128, gns + l * 128,
                                      gnw + l * 128, gnb + l * 128,
                                      normA + (size_t)l * 128, normB + (size_t)l * 128);
    }
    k_head<<<(N_ + 63) / 64, 256, 0, stream>>>(xsave, normA, normB, Wh1, bh1, Wh2, bh2,
                                               x_AA, Wo1, bo1, Wo2, bo2, Wo3, bo3,
                                               cbk, out, loss);
    k_fin<<<1, 64, 0, stream>>>(out, loss);
}